// Round 9
// baseline (315.753 us; speedup 1.0000x reference)
//
#include <hip/hip_runtime.h>
#include <hip/hip_bf16.h>

typedef __hip_bfloat16 bfloat;
typedef __bf16 bf16x8 __attribute__((ext_vector_type(8)));
typedef float f32x4 __attribute__((ext_vector_type(4)));

#define B_SZ   16384
#define E_DIM  128
#define HIST_L 50

// DTYPE MAP: inputs fp32, output fp32, internal bf16 for MFMA.
// ROUND 19: 278us. 64-MFMA/barrier @ 1 wave/SIMD == 16-MFMA/barrier @ 2
//   waves/SIMD (48.3 vs 49.3us, MfmaUtil ~25.5% both) -> barrier cadence
//   is NOT the binding constraint; MLP1 plateaued ~650-670 TF across 4
//   structures. STOP re-rolling GEMM structure.
// Ledger: visible parts (MLP1 48 + feat ~35 + pre ~19) ~100us of 278 ->
//   ~175us in never-profiled dispatches (mm, xw EPI3 scatter, MLP2, head,
//   W1c) + ~9 launch gaps.
// ROUND 20 (this): dispatch/traffic reduction, no GEMM changes.
//   (a) mm GEMM fused INTO feat_kernel as a VALU dot: d128 row in LDS
//       (broadcast reads), mmWt 32KB = L1-resident; ~3us VALU hidden
//       under gather latency; kills 1 dispatch + 16MB traffic; d128
//       stays fp32 (slightly better numerics than old MODE-3 cvt).
//   (b) mega_prep: W1c + small-prep + cvt_emb fused by blockIdx range;
//       3 pre-dispatches -> 1.
//   Launch = 6 dispatches total (was 9). MLP1 kept at r19 (best measured).

// pairs (I,J), pp=0..9: (1,2)(1,3)(1,4)(1,5)(2,3)(2,4)(2,5)(3,4)(3,5)(4,5)
// xs slot = I-1 (ISL), xw row = J-2 (groups by jsl below).
__device__ __constant__ int ISL[10] = {0,0,0,0,1,1,1,2,2,3};

__device__ __forceinline__ void gl_lds16(const void* g, void* l) {
    __builtin_amdgcn_global_load_lds(
        (const __attribute__((address_space(1))) unsigned int*)g,
        (__attribute__((address_space(3))) unsigned int*)l, 16, 0, 0);
}

// ---------------------------------------------------------------- features
// 256 threads = 2 batch rows per block. mm computed IN-KERNEL (r20):
// acc = mm_b[e] + sum_k d128[b][k] * mmW[k][e], via LDS-staged d128 row
// (broadcast) x mmWt row e (bf16, 32KB table = L1-resident).
// TB=1: item table is bf16 (itemb, row0 zeroed). TB=0: fp32 item_emb.
template<int TB>
__global__ __launch_bounds__(256) void feat_kernel(
    const int* __restrict__ item_id,
    const int* __restrict__ likes, const int* __restrict__ views,
    const int* __restrict__ seq,
    const void* __restrict__ item_tab, const float* __restrict__ cate_emb,
    const float* __restrict__ d128, const bfloat* __restrict__ mmWt,
    const float* __restrict__ mm_b,
    const float* __restrict__ ln_g, const float* __restrict__ ln_b,
    const float* __restrict__ se_W1, const float* __restrict__ se_b1,
    const float* __restrict__ se_W2, const float* __restrict__ se_b2,
    bfloat* __restrict__ xs)
{
    const int tid = threadIdx.x;
    const int r   = tid >> 7;            // sub-row 0/1
    const int e   = tid & 127;
    const int b   = blockIdx.x * 2 + r;
    const int w   = tid >> 6;            // wave 0..3 (row = w>>1)

    __shared__ float redh[2][4][128];
    __shared__ float d128s[2][128];
    __shared__ int   seq_s[2][64];
    __shared__ float lnred[4], lnred2[4];
    __shared__ float zred[5][4];
    __shared__ float wsh[2][6];
    __shared__ int   cnt_s[2];

    if (e < 64) seq_s[r][e] = (e < HIST_L) ? seq[(size_t)b * HIST_L + e] : 0;
    d128s[r][e] = d128[(size_t)b * 128 + e];
    __syncthreads();

    // long-latency gathers first
    const int iid = item_id[b];
    const float like_v = cate_emb[likes[b] * 128 + e];
    const float view_v = cate_emb[views[b] * 128 + e];
    float item_v;
    if (TB) {
        const bfloat* tb = (const bfloat*)item_tab;
        item_v = __bfloat162float(tb[(size_t)iid * 128 + e]);  // row0 zeroed
    } else {
        const float* tf = (const float*)item_tab;
        float raw = tf[(size_t)iid * 128 + e];
        item_v = iid ? raw : 0.f;
    }

    const int q   = e >> 5;
    const int l32 = e & 31;
    float4 hs = make_float4(0.f, 0.f, 0.f, 0.f);
    if (TB) {
        const ushort* tb = (const ushort*)item_tab;
        #pragma unroll
        for (int g = 0; g < 13; ++g) {
            int s = seq_s[r][g * 4 + q];
            ushort4 v = *(const ushort4*)&tb[(size_t)s * 128 + l32 * 4];
            hs.x += __bfloat162float(__ushort_as_bfloat16(v.x));
            hs.y += __bfloat162float(__ushort_as_bfloat16(v.y));
            hs.z += __bfloat162float(__ushort_as_bfloat16(v.z));
            hs.w += __bfloat162float(__ushort_as_bfloat16(v.w));
        }
    } else {
        const float* tf = (const float*)item_tab;
        #pragma unroll
        for (int g = 0; g < 13; ++g) {
            int s = seq_s[r][g * 4 + q];
            const float4 v = *(const float4*)&tf[(size_t)s * 128 + l32 * 4];
            float m = (s != 0) ? 1.f : 0.f;
            hs.x = fmaf(v.x, m, hs.x);
            hs.y = fmaf(v.y, m, hs.y);
            hs.z = fmaf(v.z, m, hs.z);
            hs.w = fmaf(v.w, m, hs.w);
        }
    }

    // mm dot (r20): acc = mm_b[e] + d128s[r][:] . mmWt[e][:]
    // d128s reads are broadcast (free); mmWt row e streams from L1/L2.
    float acc = mm_b[e];
    {
        const ushort* wrow = (const ushort*)(mmWt + (size_t)e * 128);
        #pragma unroll
        for (int k8 = 0; k8 < 16; ++k8) {
            union { bf16x8 v; ushort s[8]; } u;
            u.v = *(const bf16x8*)&wrow[k8 * 8];
            const float* dp = &d128s[r][k8 * 8];
            #pragma unroll
            for (int j = 0; j < 8; ++j)
                acc = fmaf(dp[j],
                           __bfloat162float(__ushort_as_bfloat16(u.s[j])),
                           acc);
        }
    }

    // LayerNorm reductions (per 2-wave row)
    {
        float v = acc;
        #pragma unroll
        for (int off = 32; off > 0; off >>= 1) v += __shfl_down(v, off, 64);
        if ((tid & 63) == 0) lnred[w] = v;
    }
    __syncthreads();
    const float mu = (lnred[2 * r] + lnred[2 * r + 1]) * (1.f / 128.f);
    const float d  = acc - mu;
    {
        float v = d * d;
        #pragma unroll
        for (int off = 32; off > 0; off >>= 1) v += __shfl_down(v, off, 64);
        if ((tid & 63) == 0) lnred2[w] = v;
    }
    redh[r][q][l32 * 4 + 0] = hs.x;
    redh[r][q][l32 * 4 + 1] = hs.y;
    redh[r][q][l32 * 4 + 2] = hs.z;
    redh[r][q][l32 * 4 + 3] = hs.w;
    if ((w & 1) == 0 && e < 64) {       // first wave of each row
        bool valid = (e < HIST_L) && (seq_s[r][e] != 0);
        unsigned long long m = __ballot(valid);
        if (e == 0) cnt_s[r] = (int)__popcll(m);
    }
    __syncthreads();
    const float var = (lnred2[2 * r] + lnred2[2 * r + 1]) * (1.f / 128.f);
    float xmm = d * rsqrtf(var + 1e-5f) * ln_g[e] + ln_b[e];
    xmm = fmaxf(xmm, 0.f);

    const int cnt = cnt_s[r] > 0 ? cnt_s[r] : 1;
    const float hist_v = (redh[r][0][e] + redh[r][1][e] +
                          redh[r][2][e] + redh[r][3][e]) / (float)cnt;

    // SENet z means: 5 sums, one barrier
    {
        float s1 = like_v, s2 = view_v, s3 = item_v, s4 = xmm, s5 = hist_v;
        #pragma unroll
        for (int off = 32; off > 0; off >>= 1) {
            s1 += __shfl_down(s1, off, 64);
            s2 += __shfl_down(s2, off, 64);
            s3 += __shfl_down(s3, off, 64);
            s4 += __shfl_down(s4, off, 64);
            s5 += __shfl_down(s5, off, 64);
        }
        if ((tid & 63) == 0) {
            zred[0][w] = s1; zred[1][w] = s2; zred[2][w] = s3;
            zred[3][w] = s4; zred[4][w] = s5;
        }
    }
    __syncthreads();

    if (e == 0) {
        float z[6];
        z[0] = 0.f;
        #pragma unroll
        for (int f = 1; f < 6; ++f)
            z[f] = (zred[f - 1][2 * r] + zred[f - 1][2 * r + 1]) * (1.f / 128.f);
        float a[3];
        #pragma unroll
        for (int j = 0; j < 3; ++j) {
            float s = se_b1[j];
            #pragma unroll
            for (int f = 0; f < 6; ++f) s += z[f] * se_W1[f * 3 + j];
            a[j] = fmaxf(s, 0.f);
        }
        #pragma unroll
        for (int f = 0; f < 6; ++f) {
            float s = se_b2[f];
            #pragma unroll
            for (int j = 0; j < 3; ++j) s += a[j] * se_W2[j * 6 + f];
            wsh[r][f] = 1.f / (1.f + expf(-s));
        }
    }
    __syncthreads();

    bfloat* xrow = xs + (size_t)b * 640;      // fields 1..5 at slots 0..4
    xrow[0 * 128 + e] = __float2bfloat16(like_v * wsh[r][1]);
    xrow[1 * 128 + e] = __float2bfloat16(view_v * wsh[r][2]);
    xrow[2 * 128 + e] = __float2bfloat16(item_v * wsh[r][3]);
    xrow[3 * 128 + e] = __float2bfloat16(xmm    * wsh[r][4]);
    xrow[4 * 128 + e] = __float2bfloat16(hist_v * wsh[r][5]);
}

// ---------------------------------------------------------------- pre-pass
// ONE kernel (r20), partitioned by blockIdx:
//   blocks 0..239    : W1 compact transpose, LDS-tiled (30 x 8 tiles)
//   blocks 240..883  : W2t/bWt/mmWt transposes + BN folding
//   blocks 884..6616 : item_emb fp32 -> bf16 table (row 0 zeroed)
__global__ __launch_bounds__(256) void mega_prep(
    const float* __restrict__ W1, bfloat* __restrict__ W1t,
    const float* __restrict__ W2, const float* __restrict__ bi_W,
    const float* __restrict__ mm_W,
    bfloat* __restrict__ W2t, bfloat* __restrict__ bWt,
    bfloat* __restrict__ mmWt,
    const float* __restrict__ lb1, const float* __restrict__ g1,
    const float* __restrict__ bb1, const float* __restrict__ rm1,
    const float* __restrict__ rv1,
    const float* __restrict__ lb2, const float* __restrict__ g2,
    const float* __restrict__ bb2, const float* __restrict__ rm2,
    const float* __restrict__ rv2,
    float* __restrict__ S1, float* __restrict__ T1,
    float* __restrict__ S2, float* __restrict__ T2,
    const float* __restrict__ item_emb, bfloat* __restrict__ itemb)
{
    const int blk = blockIdx.x;
    const int tid = threadIdx.x;
    if (blk < 240) {
        // W1t[n][kk] = W1[orig(kk)][n], orig = kk + (kk<640?128:768)
        __shared__ float t[64][65];
        const int kk0 = (blk % 30) * 64, n0 = (blk / 30) * 64;
        const int j = tid & 63;
        #pragma unroll
        for (int p = 0; p < 16; ++p) {
            int i = (tid >> 6) + p * 4;
            int kk = kk0 + i;
            int orig = kk + (kk < 640 ? 128 : 768);
            t[i][j] = W1[(size_t)orig * 512 + n0 + j];
        }
        __syncthreads();
        #pragma unroll
        for (int p = 0; p < 16; ++p) {
            int i = (tid >> 6) + p * 4;
            W1t[(size_t)(n0 + i) * 1920 + kk0 + j] = __float2bfloat16(t[j][i]);
        }
    } else if (blk < 884) {
        int idx = (blk - 240) * 256 + tid;
        if (idx < 131072) {                    // W2t: (512,256) -> (256,512)
            int k = idx >> 8, n = idx & 255;
            W2t[(size_t)n * 512 + k] = __float2bfloat16(W2[idx]);
        } else if (idx < 147456) {             // bWt: 128x128 transpose
            int t2 = idx - 131072;
            int k = t2 >> 7, n = t2 & 127;
            bWt[n * 128 + k] = __float2bfloat16(bi_W[t2]);
        } else if (idx < 163840) {             // mmWt: 128x128 transpose
            int t2 = idx - 147456;
            int k = t2 >> 7, n = t2 & 127;
            mmWt[n * 128 + k] = __float2bfloat16(mm_W[t2]);
        } else if (idx < 164352) {             // S1/T1
            int j = idx - 163840;
            float s = g1[j] * rsqrtf(rv1[j] + 1e-5f);
            S1[j] = s;
            T1[j] = (lb1[j] - rm1[j]) * s + bb1[j];
        } else if (idx < 164608) {             // S2/T2
            int j = idx - 164352;
            float s = g2[j] * rsqrtf(rv2[j] + 1e-5f);
            S2[j] = s;
            T2[j] = (lb2[j] - rm2[j]) * s + bb2[j];
        }
    } else {
        if (itemb == nullptr) return;
        const int n8 = 91718 * 128 / 8;
        int idx = (blk - 884) * 256 + tid;
        if (idx >= n8) return;
        if (idx < 16) {                        // row 0 zeroed (padding_idx)
            union { bf16x8 v; unsigned short s[8]; } z;
            #pragma unroll
            for (int i = 0; i < 8; ++i) z.s[i] = 0;
            ((bf16x8*)itemb)[idx] = z.v;
            return;
        }
        float4 f0 = ((const float4*)item_emb)[idx * 2];
        float4 f1 = ((const float4*)item_emb)[idx * 2 + 1];
        union { bf16x8 v; unsigned short s[8]; } u;
        u.s[0] = __bfloat16_as_ushort(__float2bfloat16(f0.x));
        u.s[1] = __bfloat16_as_ushort(__float2bfloat16(f0.y));
        u.s[2] = __bfloat16_as_ushort(__float2bfloat16(f0.z));
        u.s[3] = __bfloat16_as_ushort(__float2bfloat16(f0.w));
        u.s[4] = __bfloat16_as_ushort(__float2bfloat16(f1.x));
        u.s[5] = __bfloat16_as_ushort(__float2bfloat16(f1.y));
        u.s[6] = __bfloat16_as_ushort(__float2bfloat16(f1.z));
        u.s[7] = __bfloat16_as_ushort(__float2bfloat16(f1.w));
        ((bf16x8*)itemb)[idx] = u.v;
    }
}

// ---------------------------------------------------------------- MLP1 GEMM
// (r19, unchanged — measured 48.3us.)
// h1 = relu(BN1([xs|P] @ W1t^T)). Tile 256x128, BK=64, 1 block/CU.
// 3 dynamic-LDS buffers x 48KB; 4 waves (1/SIMD), 64 MFMA + 24 ds_read
// per K-tile per wave; counted vmcnt(12) pipeline; swizzle c^(row&7).
__global__ __launch_bounds__(256, 1) void gemm_mlp1(
    const bfloat* __restrict__ Axs, const bfloat* __restrict__ Ap,
    const bfloat* __restrict__ Bt, bfloat* __restrict__ C,
    int M, int N, int K,
    const float* __restrict__ S, const float* __restrict__ T)
{
    extern __shared__ __align__(16) short smem[];   // 3 x 24576 shorts

    const int tid  = threadIdx.x;
    const int bm   = blockIdx.x * 256;
    const int bn   = blockIdx.y * 128;
    const int wave = tid >> 6;
    const int lane = tid & 63;
    const int wm   = (wave >> 1) * 128;
    const int wn   = (wave & 1) * 64;

    const short* Ag  = (const short*)Axs;
    const short* A2g = (const short*)Ap;
    const short* Bg  = (const short*)Bt;

    f32x4 acc[8][4];
    #pragma unroll
    for (int i = 0; i < 8; ++i)
        #pragma unroll
        for (int j = 0; j < 4; ++j)
            acc[i][j] = (f32x4){0.f, 0.f, 0.f, 0.f};

    const int l8  = lane >> 3;          // == staged row & 7
    const int gch = (lane & 7) ^ l8;    // global chunk for this lane

    auto stage = [&](int buf, int kt) {
        short* Ab = smem + buf * 24576;
        short* Bb = Ab + 16384;
        #pragma unroll
        for (int d = 0; d < 4; ++d) {              // B: 4 DMAs
            int seg = wave * 4 + d;
            int row = seg * 8 + l8;
            gl_lds16(&Bg[(long)(bn + row) * K + kt + gch * 8],
                     &Bb[seg * 512 + lane * 8]);
        }
        #pragma unroll
        for (int d = 0; d < 8; ++d) {              // A: 8 DMAs
            int seg = wave * 8 + d;
            int row = seg * 8 + l8;
            long rb = (long)(bm + row);
            const short* src = (kt < 640)
                ? &Ag [rb * 640  + kt + gch * 8]
                : &A2g[rb * 1280 + (kt - 640) + gch * 8];
            gl_lds16(src, &Ab[seg * 512 + lane * 8]);
        }
    };

    const int rbase = lane & 15;
    const int rsw   = rbase & 7;

    const int nk = K >> 6;              // 30
    stage(0, 0);
    stage(1, 64);

    for (int i = 0; i < nk; ++i) {
        if (i + 1 < nk) asm volatile("s_waitcnt vmcnt(12)" ::: "memory");
        else            asm volatile("s_waitcnt vmcnt(0)" ::: "memory");
        __builtin_amdgcn_s_barrier();
        __builtin_amdgcn_sched_barrier(0);

        if (i + 2 < nk) stage((i + 2) % 3, (i + 2) << 6);

        const short* Ab = smem + (i % 3) * 24576;
        const short* Bb = Ab + 16384;
        #pragma unroll
        for (int h = 0; h < 2; ++h) {
            const int cg = h * 4 + (lane >> 4);     // global chunk 0..7
            const int ca = (cg ^ rsw) << 3;         // swizzled, shorts
            bf16x8 af[8], bfr[4];
            #pragma unroll
            for (int mt = 0; mt < 8; ++mt)
                af[mt] = *(const bf16x8*)
                    &Ab[(wm + mt * 16 + rbase) * 64 + ca];
            #pragma unroll
            for (int nt = 0; nt < 4; ++nt)
                bfr[nt] = *(const bf16x8*)
                    &Bb[(wn + nt * 16 + rbase) * 64 + ca];
            #pragma unroll
            for (int mt = 0; mt < 8; ++mt)
                #pragma unroll
                for (int nt = 0; nt < 4; ++nt)
                    acc[mt][nt] = __builtin_amdgcn_mfma_f32_16x16x32_bf16(
                        af[mt], bfr[nt], acc[mt][nt], 0, 0, 0);
        }
    }

    // epilogue: relu(acc*S+T); C/D layout col = lane&15, row = (lane>>4)*4+i
    const int col0 = lane & 15;
    const int row0 = (lane >> 4) * 4;
    #pragma unroll
    for (int nt = 0; nt < 4; ++nt) {
        int col = bn + wn + nt * 16 + col0;
        float s = S[col], t = T[col];
        #pragma unroll
        for (int mt = 0; mt < 8; ++mt) {
            #pragma unroll
            for (int i = 0; i < 4; ++i) {
                int row = bm + wm + mt * 16 + row0 + i;
                float v = fmaxf(acc[mt][nt][i] * s + t, 0.f);
                C[(size_t)row * N + col] = __float2bfloat16(v);
            }
        }
    }
}

// ---------------------------------------------------------------- MFMA GEMM
// (r18 template — used for xw (MODE 2/EPI 3) and MLP2 (MODE 0/EPI 1).)
// Tile 128x128, BK=32, depth-3 counted-vmcnt pipeline over 4 LDS buffers.
template<int MODE, int EPI, int F32OUT>
__global__ __launch_bounds__(256, 2) void gemm_bt(
    const void* __restrict__ A, const bfloat* __restrict__ A2,
    const bfloat* __restrict__ Bt, void* __restrict__ C,
    int M, int N, int K,
    const float* __restrict__ S, const float* __restrict__ T)
{
    __shared__ __align__(16) short As[4][128 * 32];
    __shared__ __align__(16) short Bs[4][128 * 32];

    const int tid  = threadIdx.x;
    const int bm   = blockIdx.x * 128;
    const int bn   = blockIdx.y * 128;
    const int wave = tid >> 6;
    const int lane = tid & 63;
    const int wm   = (wave >> 1) * 64;
    const int wn   = (wave & 1) * 64;

    const short* Ag  = (const short*)A;
    const short* Bg  = (const short*)Bt;

    f32x4 acc[4][4];
    #pragma unroll
    for (int i = 0; i < 4; ++i)
        #pragma unroll
        for (int j = 0; j < 4; ++j)
            acc[i][j] = (f32x4){0.f, 0.f, 0.f, 0.f};

    const int srow = tid >> 2;          // 0..63 (staging row within pass)
    const int sck  = tid & 3;           // dest 16B chunk within 64B row

    auto stage = [&](int buf, int kt) {
        #pragma unroll
        for (int rr = 0; rr < 2; ++rr) {           // B: 2 DMAs
            int row = srow + rr * 64;
            int g   = sck ^ ((row >> 1) & 3);      // swizzled global chunk
            gl_lds16(&Bg[(long)(bn + row) * K + kt + g * 8],
                     &Bs[buf][row * 32 + sck * 8]);
        }
        #pragma unroll
        for (int rr = 0; rr < 2; ++rr) {           // A: 2 DMAs
            int row = srow + rr * 64;
            int g   = sck ^ ((row >> 1) & 3);
            const short* src;
            if (MODE == 2) {
                int gr = bm + row;
                src = &Ag[((long)(gr >> 2)) * 640 +
                          ((gr & 3) + 1) * 128 + kt + g * 8];
            } else {
                src = &Ag[(long)(bm + row) * K + kt + g * 8];
            }
            gl_lds16(src, &As[buf][row * 32 + sck * 8]);
        }
    };

    const int rbase = lane & 15;
    const int cg    = lane >> 4;        // k-chunk 0..3
    const int ca    = (cg ^ ((rbase >> 1) & 3)) << 3;   // swizzled, shorts

    const int nk = K >> 5;              // >= 4 for all our shapes
    stage(0, 0);
    stage(1, 32);
    if (nk > 2) stage(2, 64);

    for (int i = 0; i < nk; ++i) {
        if (i + 2 < nk)
            asm volatile("s_waitcnt vmcnt(8)" ::: "memory");
        else if (i + 1 < nk)
            asm volatile("s_waitcnt vmcnt(4)" ::: "memory");
        else
            asm volatile("s_waitcnt vmcnt(0)" ::: "memory");
        __builtin_amdgcn_s_barrier();
        __builtin_amdgcn_sched_barrier(0);

        const int cur = i & 3;
        bf16x8 af[4], bfr[4];
        #pragma unroll
        for (int mt = 0; mt < 4; ++mt)
            af[mt] = *(const bf16x8*)
                &As[cur][(wm + mt * 16 + rbase) * 32 + ca];
        #pragma unroll
        for (int nt = 0; nt < 4; ++nt)
            bfr[nt] = *(const bf16x8*)
                &Bs[cur][(wn + nt * 16 + rbase) * 32 + ca];
        #pragma unroll
        for (int mt = 0; mt < 4; ++mt)
            #pragma unroll
            for (int nt = 0; nt < 4; ++nt)
                acc[mt][nt] = __builtin_amdgcn_mfma_f32_16x16x32_bf16(
                    af[mt], bfr[nt], acc[mt][nt], 0, 0, 0);

        if (i + 3 < nk) stage((i + 3) & 3, (i + 3) << 5);
    }

    // epilogue: C/D layout col = lane&15, row = (lane>>4)*4 + i
    const int col0 = lane & 15;
    const int row0 = (lane >> 4) * 4;
    #pragma unroll
    for (int nt = 0; nt < 4; ++nt) {
        int col = bn + wn + nt * 16 + col0;
        float s = 1.f, t = 0.f;
        if (EPI == 1 || EPI == 2) { s = (EPI == 1) ? S[col] : 1.f; t = T[col]; }
        #pragma unroll
        for (int mt = 0; mt < 4; ++mt) {
            #pragma unroll
            for (int i = 0; i < 4; ++i) {
                int row = bm + wm + mt * 16 + row0 + i;
                float v = acc[mt][nt][i];
                if (EPI == 3) {
                    // row = b*4 + jsl, jsl == i (bm,wm,mt*16,row0 all %4==0)
                    const bfloat* xsp = (const bfloat*)A;
                    bfloat* Pp = (bfloat*)C;
                    long b = row >> 2;
                    int pplist[4];
                    int npp;
                    if (i == 0)      { npp = 1; pplist[0] = 0; }
                    else if (i == 1) { npp = 2; pplist[0] = 1; pplist[1] = 4; }
                    else if (i == 2) { npp = 3; pplist[0] = 2; pplist[1] = 5; pplist[2] = 7; }
                    else             { npp = 4; pplist[0] = 3; pplist[1] = 6; pplist[2] = 8; pplist[3] = 9; }
                    #pragma unroll
                    for (int t2 = 0; t2 < npp; ++t2) {
                        int pp  = pplist[t2];
                        int isl = ISL[pp];
                        float xv = __bfloat162float(
                            xsp[b * 640 + isl * 128 + col]);
                        Pp[b * 1280 + pp * 128 + col] =
                            __float2bfloat16(xv * v);
                    }
                } else {
                    if (EPI == 1) v = fmaxf(v * s + t, 0.f);
                    if (EPI == 2) v = v + t;
                    if (F32OUT) ((float*)C)[(size_t)row * N + col] = v;
                    else ((bfloat*)C)[(size_t)row * N + col] = __float2bfloat16(v);
                }
            }
        }
    }
}

// ---------------------------------------------------------------- head
__global__ __launch_bounds__(256) void head_kernel(
    const bfloat* __restrict__ h2, const float* __restrict__ W3,
    const float* __restrict__ b3, float* __restrict__ out)
{
    int lane = threadIdx.x & 63;
    int row  = blockIdx.x * 4 + (threadIdx.x >> 6);
    float acc = 0.f;
    #pragma unroll
    for (int i = 0; i < 4; ++i)
        acc += __bfloat162float(h2[(size_t)row * 256 + i * 64 + lane]) *
               W3[i * 64 + lane];
    #pragma unroll
    for (int off = 32; off > 0; off >>= 1) acc += __shfl_down(acc, off, 64);
    if (lane == 0) {
        float l = acc + b3[0];
        out[row] = 1.f / (1.f + expf(-l));
    }
}

// ---------------------------------------------------------------- launch
extern "C" void kernel_launch(void* const* d_in, const int* in_sizes, int n_in,
                              void* d_out, int out_size, void* d_ws, size_t ws_size,
                              hipStream_t stream) {
    const int*   item_id = (const int*)  d_in[0];
    const float* d128    = (const float*)d_in[1];
    const int*   likes   = (const int*)  d_in[2];
    const int*   views   = (const int*)  d_in[3];
    const int*   seq     = (const int*)  d_in[4];
    const float* item_emb= (const float*)d_in[5];
    const float* cate_emb= (const float*)d_in[6];
    const float* mm_W    = (const float*)d_in[7];
    const float* mm_b    = (const float*)d_in[8];
    const float* ln_g    = (const float*)d_in[9];
    const float* ln_b    = (const float*)d_in[10];
    const float* se_W1   = (const float*)d_in[11];
    const float* se_b1   = (const float*)d_in[12];
    const float* se_W2   = (const float*)d_in[13];
    const float* se_b2   = (const float*)d_in[14];
    const float* bi_W    = (const float*)d_in[15];
    const float* W1      = (const float*)d_in[16];
    const float* b1      = (const float*)d_in[17];
    const float* bn1_g   = (const float*)d_in[18];
    const float* bn1_b   = (const float*)d_in[19];
    const float* bn1_rm  = (const float*)d_in[20];
    const float* bn1_rv  = (const float*)d_in[21];
    const float* W2      = (const float*)d_in[22];
    const float* b2      = (const float*)d_in[23];
    const float* bn2_g   = (const float*)d_in[24];
    const float* bn2_b   = (const float*)d_in[25];
    const float* bn2_rm  = (const float*)d_in[26];
    const float* bn2_rv  = (const float*)d_in[27];
    const float* W3      = (const float*)d_in[28];
    const float* b3      = (const float*)d_in[29];

    // --------- workspace (ws ~ 268MB per round-14 fill evidence) --------
    // fixed: W1t 1,966,080 | W2t 262,144 | bWt 32,768 | mmWt 32,768 |
    //        S1/T1 4,096 | S2/T2 2,048 | pad 512 = 2,300,416 B
    // itemb (optional): 91718*128*2 = 23,479,808 B
    // per-row 4864 B: xs 1280 | h1 1024 | P 2560. h2 aliases P (post-MLP1).
    const size_t fixed = 2300416;
    const size_t ITB   = 23479808;
    int CH; bool use_tb;
    if      (fixed + ITB + (size_t)16384 * 4864 <= ws_size) { CH = 16384; use_tb = true;  }
    else if (fixed + (size_t)16384 * 4864 <= ws_size)       { CH = 16384; use_tb = false; }
    else if (fixed + ITB + (size_t)8192 * 4864 <= ws_size)  { CH = 8192;  use_tb = true;  }
    else if (fixed + (size_t)8192 * 4864 <= ws_size)        { CH = 8192;  use_tb = false; }
    else if (fixed + ITB + (size_t)4096 * 4864 <= ws_size)  { CH = 4096;  use_tb = true;  }
    else if (fixed + (size_t)4096 * 4864 <= ws_size)        { CH = 4096;  use_tb = false; }
    else if (fixed + (size_t)2048 * 4864 <= ws_size)        { CH = 2048;  use_tb = false; }
    else                                                    { CH = 1024;  use_tb = false; }

    char* ws = (char*)d_ws;
    bfloat* W1t = (bfloat*)(ws);                 // 1,966,080
    bfloat* W2t = (bfloat*)(ws + 1966080);       //   262,144
    bfloat* bWt = (bfloat*)(ws + 2228224);       //    32,768
    bfloat* mmWt= (bfloat*)(ws + 2260992);       //    32,768
    float*  S1  = (float*) (ws + 2293760);       //     2,048
    float*  T1  = (float*) (ws + 2295808);       //     2,048
    float*  S2  = (float*) (ws + 2297856);       //     1,024
    float*  T2  = (float*) (ws + 2298880);       //     1,024
    bfloat* itemb = (bfloat*)(ws + fixed);       // ITB (if use_tb)
    char*   cb  = ws + fixed + (use_tb ? ITB : 0);
    bfloat* xs  = (bfloat*)(cb);                            // CH*1280 B
    bfloat* h1  = (bfloat*)(cb + (size_t)CH * 1280);        // CH*1024 B
    bfloat* P   = (bfloat*)(cb + (size_t)CH * 2304);        // CH*2560 B
    bfloat* h2  = (bfloat*)P;                               // alias (post-MLP1)

    // single fused pre-pass: W1c tiles + small prep + (optional) cvt_emb
    {
        int nblk = 884 + (use_tb ? (91718 * 128 / 8 + 255) / 256 : 0);
        mega_prep<<<nblk, 256, 0, stream>>>(
            W1, W1t, W2, bi_W, mm_W, W2t, bWt, mmWt,
            b1, bn1_g, bn1_b, bn1_rm, bn1_rv,
            b2, bn2_g, bn2_b, bn2_rm, bn2_rv,
            S1, T1, S2, T2,
            item_emb, use_tb ? itemb : nullptr);
    }

    for (int off = 0; off < B_SZ; off += CH) {
        // feat (mm fused in-kernel from d128 x mmWt + mm_b)
        if (use_tb)
            feat_kernel<1><<<CH / 2, 256, 0, stream>>>(
                item_id + off, likes + off, views + off,
                seq + (size_t)off * HIST_L, itemb, cate_emb,
                d128 + (size_t)off * 128, mmWt, mm_b,
                ln_g, ln_b, se_W1, se_b1, se_W2, se_b2, xs);
        else
            feat_kernel<0><<<CH / 2, 256, 0, stream>>>(
                item_id + off, likes + off, views + off,
                seq + (size_t)off * HIST_L, item_emb, cate_emb,
                d128 + (size_t)off * 128, mmWt, mm_b,
                ln_g, ln_b, se_W1, se_b1, se_W2, se_b2, xs);

        // xw GEMM + fused pair epilogue: writes P directly.
        dim3 gxw(CH * 4 / 128, 1);
        gemm_bt<2, 3, 0><<<gxw, 256, 0, stream>>>(
            xs, nullptr, bWt, P, CH * 4, 128, 128, nullptr, nullptr);

        // h1 = relu(BN1([xs|P] @ W1t^T)): K = 1920 (r19 kernel)
        dim3 g1(CH / 256, 4);
        gemm_mlp1<<<g1, 256, 147456, stream>>>(
            xs, P, W1t, h1, CH, 512, 1920, S1, T1);

        // h2 = relu(BN2(h1 @ W2)): K = 512  (h2 overwrites P - dead)
        dim3 g2(CH / 128, 2);
        gemm_bt<0, 1, 0><<<g2, 256, 0, stream>>>(
            h1, nullptr, W2t, h2, CH, 256, 512, S2, T2);

        head_kernel<<<CH / 4, 256, 0, stream>>>(h2, W3, b3, (float*)d_out + off);
    }
}

// Round 10
// 291.557 us; speedup vs baseline: 1.0830x; 1.0830x over previous
//
#include <hip/hip_runtime.h>
#include <hip/hip_bf16.h>

typedef __hip_bfloat16 bfloat;
typedef __bf16 bf16x8 __attribute__((ext_vector_type(8)));
typedef float f32x4 __attribute__((ext_vector_type(4)));

#define B_SZ   16384
#define E_DIM  128
#define HIST_L 50

// DTYPE MAP: inputs fp32, output fp32, internal bf16 for MFMA.
// ROUND 20 pm: REGRESSED 315.8 (feat 97.7us). mm-dot fusion used
//   mmWt[e][k] with e=lane -> 256B-strided per-lane rows: every load
//   touches 64 cache lines (worst-case gather) + 128-deep serial fmaf
//   chain = +45us on feat. Ledger confirmed: feat-with-table ~50us,
//   mm GEMM only ~8us.
// ROUND 21 (this): keep the fusion, fix the pattern: broadcast-k /
//   coalesced-e. mmWb = bf16 cast of mm_W in ORIGINAL [k][e] layout
//   (no transpose; replaces mmWt). Inner loop: d128s[k..k+3] is an LDS
//   broadcast (uniform addr = free); mmWb[k*128+e] is one 128B coalesced
//   L1 line per wave (32KB table = L1-resident). 4 partial accumulators
//   break the fmaf chain. Everything else unchanged from r20.

// pairs (I,J), pp=0..9: (1,2)(1,3)(1,4)(1,5)(2,3)(2,4)(2,5)(3,4)(3,5)(4,5)
// xs slot = I-1 (ISL), xw row = J-2 (groups by jsl below).
__device__ __constant__ int ISL[10] = {0,0,0,0,1,1,1,2,2,3};

__device__ __forceinline__ void gl_lds16(const void* g, void* l) {
    __builtin_amdgcn_global_load_lds(
        (const __attribute__((address_space(1))) unsigned int*)g,
        (__attribute__((address_space(3))) unsigned int*)l, 16, 0, 0);
}

// ---------------------------------------------------------------- features
// 256 threads = 2 batch rows per block. mm computed in-kernel:
// acc = mm_b[e] + sum_k d128[b][k] * mmW[k][e]; d128 row staged in LDS
// (broadcast reads over k), mmWb bf16 [k][e] read coalesced over e.
// TB=1: item table is bf16 (itemb, row0 zeroed). TB=0: fp32 item_emb.
template<int TB>
__global__ __launch_bounds__(256) void feat_kernel(
    const int* __restrict__ item_id,
    const int* __restrict__ likes, const int* __restrict__ views,
    const int* __restrict__ seq,
    const void* __restrict__ item_tab, const float* __restrict__ cate_emb,
    const float* __restrict__ d128, const bfloat* __restrict__ mmWb,
    const float* __restrict__ mm_b,
    const float* __restrict__ ln_g, const float* __restrict__ ln_b,
    const float* __restrict__ se_W1, const float* __restrict__ se_b1,
    const float* __restrict__ se_W2, const float* __restrict__ se_b2,
    bfloat* __restrict__ xs)
{
    const int tid = threadIdx.x;
    const int r   = tid >> 7;            // sub-row 0/1
    const int e   = tid & 127;
    const int b   = blockIdx.x * 2 + r;
    const int w   = tid >> 6;            // wave 0..3 (row = w>>1)

    __shared__ float redh[2][4][128];
    __shared__ float d128s[2][128];
    __shared__ int   seq_s[2][64];
    __shared__ float lnred[4], lnred2[4];
    __shared__ float zred[5][4];
    __shared__ float wsh[2][6];
    __shared__ int   cnt_s[2];

    if (e < 64) seq_s[r][e] = (e < HIST_L) ? seq[(size_t)b * HIST_L + e] : 0;
    d128s[r][e] = d128[(size_t)b * 128 + e];
    __syncthreads();

    // long-latency gathers first
    const int iid = item_id[b];
    const float like_v = cate_emb[likes[b] * 128 + e];
    const float view_v = cate_emb[views[b] * 128 + e];
    float item_v;
    if (TB) {
        const bfloat* tb = (const bfloat*)item_tab;
        item_v = __bfloat162float(tb[(size_t)iid * 128 + e]);  // row0 zeroed
    } else {
        const float* tf = (const float*)item_tab;
        float raw = tf[(size_t)iid * 128 + e];
        item_v = iid ? raw : 0.f;
    }

    const int q   = e >> 5;
    const int l32 = e & 31;
    float4 hs = make_float4(0.f, 0.f, 0.f, 0.f);
    if (TB) {
        const ushort* tb = (const ushort*)item_tab;
        #pragma unroll
        for (int g = 0; g < 13; ++g) {
            int s = seq_s[r][g * 4 + q];
            ushort4 v = *(const ushort4*)&tb[(size_t)s * 128 + l32 * 4];
            hs.x += __bfloat162float(__ushort_as_bfloat16(v.x));
            hs.y += __bfloat162float(__ushort_as_bfloat16(v.y));
            hs.z += __bfloat162float(__ushort_as_bfloat16(v.z));
            hs.w += __bfloat162float(__ushort_as_bfloat16(v.w));
        }
    } else {
        const float* tf = (const float*)item_tab;
        #pragma unroll
        for (int g = 0; g < 13; ++g) {
            int s = seq_s[r][g * 4 + q];
            const float4 v = *(const float4*)&tf[(size_t)s * 128 + l32 * 4];
            float m = (s != 0) ? 1.f : 0.f;
            hs.x = fmaf(v.x, m, hs.x);
            hs.y = fmaf(v.y, m, hs.y);
            hs.z = fmaf(v.z, m, hs.z);
            hs.w = fmaf(v.w, m, hs.w);
        }
    }

    // mm dot (r21): broadcast-k / coalesced-e.
    // dv = d128s[r][k..k+3]: LDS read at wave-uniform address (broadcast).
    // mmWb[k*128+e]: per-wave e is a contiguous 64-range -> one 128B
    // coalesced L1 line per load (32KB table L1-resident).
    float acc = mm_b[e];
    {
        float a0 = 0.f, a1 = 0.f, a2 = 0.f, a3 = 0.f;
        const ushort* wb = (const ushort*)mmWb;
        #pragma unroll
        for (int k = 0; k < 128; k += 4) {
            float4 dv = *(const float4*)&d128s[r][k];
            a0 = fmaf(dv.x, __bfloat162float(__ushort_as_bfloat16(
                     wb[(k + 0) * 128 + e])), a0);
            a1 = fmaf(dv.y, __bfloat162float(__ushort_as_bfloat16(
                     wb[(k + 1) * 128 + e])), a1);
            a2 = fmaf(dv.z, __bfloat162float(__ushort_as_bfloat16(
                     wb[(k + 2) * 128 + e])), a2);
            a3 = fmaf(dv.w, __bfloat162float(__ushort_as_bfloat16(
                     wb[(k + 3) * 128 + e])), a3);
        }
        acc += (a0 + a1) + (a2 + a3);
    }

    // LayerNorm reductions (per 2-wave row)
    {
        float v = acc;
        #pragma unroll
        for (int off = 32; off > 0; off >>= 1) v += __shfl_down(v, off, 64);
        if ((tid & 63) == 0) lnred[w] = v;
    }
    __syncthreads();
    const float mu = (lnred[2 * r] + lnred[2 * r + 1]) * (1.f / 128.f);
    const float d  = acc - mu;
    {
        float v = d * d;
        #pragma unroll
        for (int off = 32; off > 0; off >>= 1) v += __shfl_down(v, off, 64);
        if ((tid & 63) == 0) lnred2[w] = v;
    }
    redh[r][q][l32 * 4 + 0] = hs.x;
    redh[r][q][l32 * 4 + 1] = hs.y;
    redh[r][q][l32 * 4 + 2] = hs.z;
    redh[r][q][l32 * 4 + 3] = hs.w;
    if ((w & 1) == 0 && e < 64) {       // first wave of each row
        bool valid = (e < HIST_L) && (seq_s[r][e] != 0);
        unsigned long long m = __ballot(valid);
        if (e == 0) cnt_s[r] = (int)__popcll(m);
    }
    __syncthreads();
    const float var = (lnred2[2 * r] + lnred2[2 * r + 1]) * (1.f / 128.f);
    float xmm = d * rsqrtf(var + 1e-5f) * ln_g[e] + ln_b[e];
    xmm = fmaxf(xmm, 0.f);

    const int cnt = cnt_s[r] > 0 ? cnt_s[r] : 1;
    const float hist_v = (redh[r][0][e] + redh[r][1][e] +
                          redh[r][2][e] + redh[r][3][e]) / (float)cnt;

    // SENet z means: 5 sums, one barrier
    {
        float s1 = like_v, s2 = view_v, s3 = item_v, s4 = xmm, s5 = hist_v;
        #pragma unroll
        for (int off = 32; off > 0; off >>= 1) {
            s1 += __shfl_down(s1, off, 64);
            s2 += __shfl_down(s2, off, 64);
            s3 += __shfl_down(s3, off, 64);
            s4 += __shfl_down(s4, off, 64);
            s5 += __shfl_down(s5, off, 64);
        }
        if ((tid & 63) == 0) {
            zred[0][w] = s1; zred[1][w] = s2; zred[2][w] = s3;
            zred[3][w] = s4; zred[4][w] = s5;
        }
    }
    __syncthreads();

    if (e == 0) {
        float z[6];
        z[0] = 0.f;
        #pragma unroll
        for (int f = 1; f < 6; ++f)
            z[f] = (zred[f - 1][2 * r] + zred[f - 1][2 * r + 1]) * (1.f / 128.f);
        float a[3];
        #pragma unroll
        for (int j = 0; j < 3; ++j) {
            float s = se_b1[j];
            #pragma unroll
            for (int f = 0; f < 6; ++f) s += z[f] * se_W1[f * 3 + j];
            a[j] = fmaxf(s, 0.f);
        }
        #pragma unroll
        for (int f = 0; f < 6; ++f) {
            float s = se_b2[f];
            #pragma unroll
            for (int j = 0; j < 3; ++j) s += a[j] * se_W2[j * 6 + f];
            wsh[r][f] = 1.f / (1.f + expf(-s));
        }
    }
    __syncthreads();

    bfloat* xrow = xs + (size_t)b * 640;      // fields 1..5 at slots 0..4
    xrow[0 * 128 + e] = __float2bfloat16(like_v * wsh[r][1]);
    xrow[1 * 128 + e] = __float2bfloat16(view_v * wsh[r][2]);
    xrow[2 * 128 + e] = __float2bfloat16(item_v * wsh[r][3]);
    xrow[3 * 128 + e] = __float2bfloat16(xmm    * wsh[r][4]);
    xrow[4 * 128 + e] = __float2bfloat16(hist_v * wsh[r][5]);
}

// ---------------------------------------------------------------- pre-pass
// ONE kernel, partitioned by blockIdx:
//   blocks 0..239    : W1 compact transpose, LDS-tiled (30 x 8 tiles)
//   blocks 240..883  : W2t/bWt transposes + mmWb cast + BN folding
//   blocks 884..     : item_emb fp32 -> bf16 table (row 0 zeroed)
__global__ __launch_bounds__(256) void mega_prep(
    const float* __restrict__ W1, bfloat* __restrict__ W1t,
    const float* __restrict__ W2, const float* __restrict__ bi_W,
    const float* __restrict__ mm_W,
    bfloat* __restrict__ W2t, bfloat* __restrict__ bWt,
    bfloat* __restrict__ mmWb,
    const float* __restrict__ lb1, const float* __restrict__ g1,
    const float* __restrict__ bb1, const float* __restrict__ rm1,
    const float* __restrict__ rv1,
    const float* __restrict__ lb2, const float* __restrict__ g2,
    const float* __restrict__ bb2, const float* __restrict__ rm2,
    const float* __restrict__ rv2,
    float* __restrict__ S1, float* __restrict__ T1,
    float* __restrict__ S2, float* __restrict__ T2,
    const float* __restrict__ item_emb, bfloat* __restrict__ itemb)
{
    const int blk = blockIdx.x;
    const int tid = threadIdx.x;
    if (blk < 240) {
        // W1t[n][kk] = W1[orig(kk)][n], orig = kk + (kk<640?128:768)
        __shared__ float t[64][65];
        const int kk0 = (blk % 30) * 64, n0 = (blk / 30) * 64;
        const int j = tid & 63;
        #pragma unroll
        for (int p = 0; p < 16; ++p) {
            int i = (tid >> 6) + p * 4;
            int kk = kk0 + i;
            int orig = kk + (kk < 640 ? 128 : 768);
            t[i][j] = W1[(size_t)orig * 512 + n0 + j];
        }
        __syncthreads();
        #pragma unroll
        for (int p = 0; p < 16; ++p) {
            int i = (tid >> 6) + p * 4;
            W1t[(size_t)(n0 + i) * 1920 + kk0 + j] = __float2bfloat16(t[j][i]);
        }
    } else if (blk < 884) {
        int idx = (blk - 240) * 256 + tid;
        if (idx < 131072) {                    // W2t: (512,256) -> (256,512)
            int k = idx >> 8, n = idx & 255;
            W2t[(size_t)n * 512 + k] = __float2bfloat16(W2[idx]);
        } else if (idx < 147456) {             // bWt: 128x128 transpose
            int t2 = idx - 131072;
            int k = t2 >> 7, n = t2 & 127;
            bWt[n * 128 + k] = __float2bfloat16(bi_W[t2]);
        } else if (idx < 163840) {             // mmWb: straight cast [k][e]
            int t2 = idx - 147456;
            mmWb[t2] = __float2bfloat16(mm_W[t2]);
        } else if (idx < 164352) {             // S1/T1
            int j = idx - 163840;
            float s = g1[j] * rsqrtf(rv1[j] + 1e-5f);
            S1[j] = s;
            T1[j] = (lb1[j] - rm1[j]) * s + bb1[j];
        } else if (idx < 164608) {             // S2/T2
            int j = idx - 164352;
            float s = g2[j] * rsqrtf(rv2[j] + 1e-5f);
            S2[j] = s;
            T2[j] = (lb2[j] - rm2[j]) * s + bb2[j];
        }
    } else {
        if (itemb == nullptr) return;
        const int n8 = 91718 * 128 / 8;
        int idx = (blk - 884) * 256 + tid;
        if (idx >= n8) return;
        if (idx < 16) {                        // row 0 zeroed (padding_idx)
            union { bf16x8 v; unsigned short s[8]; } z;
            #pragma unroll
            for (int i = 0; i < 8; ++i) z.s[i] = 0;
            ((bf16x8*)itemb)[idx] = z.v;
            return;
        }
        float4 f0 = ((const float4*)item_emb)[idx * 2];
        float4 f1 = ((const float4*)item_emb)[idx * 2 + 1];
        union { bf16x8 v; unsigned short s[8]; } u;
        u.s[0] = __bfloat16_as_ushort(__float2bfloat16(f0.x));
        u.s[1] = __bfloat16_as_ushort(__float2bfloat16(f0.y));
        u.s[2] = __bfloat16_as_ushort(__float2bfloat16(f0.z));
        u.s[3] = __bfloat16_as_ushort(__float2bfloat16(f0.w));
        u.s[4] = __bfloat16_as_ushort(__float2bfloat16(f1.x));
        u.s[5] = __bfloat16_as_ushort(__float2bfloat16(f1.y));
        u.s[6] = __bfloat16_as_ushort(__float2bfloat16(f1.z));
        u.s[7] = __bfloat16_as_ushort(__float2bfloat16(f1.w));
        ((bf16x8*)itemb)[idx] = u.v;
    }
}

// ---------------------------------------------------------------- MLP1 GEMM
// (r19, unchanged — measured 48.3us.)
// h1 = relu(BN1([xs|P] @ W1t^T)). Tile 256x128, BK=64, 1 block/CU.
// 3 dynamic-LDS buffers x 48KB; 4 waves (1/SIMD), 64 MFMA + 24 ds_read
// per K-tile per wave; counted vmcnt(12) pipeline; swizzle c^(row&7).
__global__ __launch_bounds__(256, 1) void gemm_mlp1(
    const bfloat* __restrict__ Axs, const bfloat* __restrict__ Ap,
    const bfloat* __restrict__ Bt, bfloat* __restrict__ C,
    int M, int N, int K,
    const float* __restrict__ S, const float* __restrict__ T)
{
    extern __shared__ __align__(16) short smem[];   // 3 x 24576 shorts

    const int tid  = threadIdx.x;
    const int bm   = blockIdx.x * 256;
    const int bn   = blockIdx.y * 128;
    const int wave = tid >> 6;
    const int lane = tid & 63;
    const int wm   = (wave >> 1) * 128;
    const int wn   = (wave & 1) * 64;

    const short* Ag  = (const short*)Axs;
    const short* A2g = (const short*)Ap;
    const short* Bg  = (const short*)Bt;

    f32x4 acc[8][4];
    #pragma unroll
    for (int i = 0; i < 8; ++i)
        #pragma unroll
        for (int j = 0; j < 4; ++j)
            acc[i][j] = (f32x4){0.f, 0.f, 0.f, 0.f};

    const int l8  = lane >> 3;          // == staged row & 7
    const int gch = (lane & 7) ^ l8;    // global chunk for this lane

    auto stage = [&](int buf, int kt) {
        short* Ab = smem + buf * 24576;
        short* Bb = Ab + 16384;
        #pragma unroll
        for (int d = 0; d < 4; ++d) {              // B: 4 DMAs
            int seg = wave * 4 + d;
            int row = seg * 8 + l8;
            gl_lds16(&Bg[(long)(bn + row) * K + kt + gch * 8],
                     &Bb[seg * 512 + lane * 8]);
        }
        #pragma unroll
        for (int d = 0; d < 8; ++d) {              // A: 8 DMAs
            int seg = wave * 8 + d;
            int row = seg * 8 + l8;
            long rb = (long)(bm + row);
            const short* src = (kt < 640)
                ? &Ag [rb * 640  + kt + gch * 8]
                : &A2g[rb * 1280 + (kt - 640) + gch * 8];
            gl_lds16(src, &Ab[seg * 512 + lane * 8]);
        }
    };

    const int rbase = lane & 15;
    const int rsw   = rbase & 7;

    const int nk = K >> 6;              // 30
    stage(0, 0);
    stage(1, 64);

    for (int i = 0; i < nk; ++i) {
        if (i + 1 < nk) asm volatile("s_waitcnt vmcnt(12)" ::: "memory");
        else            asm volatile("s_waitcnt vmcnt(0)" ::: "memory");
        __builtin_amdgcn_s_barrier();
        __builtin_amdgcn_sched_barrier(0);

        if (i + 2 < nk) stage((i + 2) % 3, (i + 2) << 6);

        const short* Ab = smem + (i % 3) * 24576;
        const short* Bb = Ab + 16384;
        #pragma unroll
        for (int h = 0; h < 2; ++h) {
            const int cg = h * 4 + (lane >> 4);     // global chunk 0..7
            const int ca = (cg ^ rsw) << 3;         // swizzled, shorts
            bf16x8 af[8], bfr[4];
            #pragma unroll
            for (int mt = 0; mt < 8; ++mt)
                af[mt] = *(const bf16x8*)
                    &Ab[(wm + mt * 16 + rbase) * 64 + ca];
            #pragma unroll
            for (int nt = 0; nt < 4; ++nt)
                bfr[nt] = *(const bf16x8*)
                    &Bb[(wn + nt * 16 + rbase) * 64 + ca];
            #pragma unroll
            for (int mt = 0; mt < 8; ++mt)
                #pragma unroll
                for (int nt = 0; nt < 4; ++nt)
                    acc[mt][nt] = __builtin_amdgcn_mfma_f32_16x16x32_bf16(
                        af[mt], bfr[nt], acc[mt][nt], 0, 0, 0);
        }
    }

    // epilogue: relu(acc*S+T); C/D layout col = lane&15, row = (lane>>4)*4+i
    const int col0 = lane & 15;
    const int row0 = (lane >> 4) * 4;
    #pragma unroll
    for (int nt = 0; nt < 4; ++nt) {
        int col = bn + wn + nt * 16 + col0;
        float s = S[col], t = T[col];
        #pragma unroll
        for (int mt = 0; mt < 8; ++mt) {
            #pragma unroll
            for (int i = 0; i < 4; ++i) {
                int row = bm + wm + mt * 16 + row0 + i;
                float v = fmaxf(acc[mt][nt][i] * s + t, 0.f);
                C[(size_t)row * N + col] = __float2bfloat16(v);
            }
        }
    }
}

// ---------------------------------------------------------------- MFMA GEMM
// (r18 template — used for xw (MODE 2/EPI 3) and MLP2 (MODE 0/EPI 1).)
// Tile 128x128, BK=32, depth-3 counted-vmcnt pipeline over 4 LDS buffers.
template<int MODE, int EPI, int F32OUT>
__global__ __launch_bounds__(256, 2) void gemm_bt(
    const void* __restrict__ A, const bfloat* __restrict__ A2,
    const bfloat* __restrict__ Bt, void* __restrict__ C,
    int M, int N, int K,
    const float* __restrict__ S, const float* __restrict__ T)
{
    __shared__ __align__(16) short As[4][128 * 32];
    __shared__ __align__(16) short Bs[4][128 * 32];

    const int tid  = threadIdx.x;
    const int bm   = blockIdx.x * 128;
    const int bn   = blockIdx.y * 128;
    const int wave = tid >> 6;
    const int lane = tid & 63;
    const int wm   = (wave >> 1) * 64;
    const int wn   = (wave & 1) * 64;

    const short* Ag  = (const short*)A;
    const short* Bg  = (const short*)Bt;

    f32x4 acc[4][4];
    #pragma unroll
    for (int i = 0; i < 4; ++i)
        #pragma unroll
        for (int j = 0; j < 4; ++j)
            acc[i][j] = (f32x4){0.f, 0.f, 0.f, 0.f};

    const int srow = tid >> 2;          // 0..63 (staging row within pass)
    const int sck  = tid & 3;           // dest 16B chunk within 64B row

    auto stage = [&](int buf, int kt) {
        #pragma unroll
        for (int rr = 0; rr < 2; ++rr) {           // B: 2 DMAs
            int row = srow + rr * 64;
            int g   = sck ^ ((row >> 1) & 3);      // swizzled global chunk
            gl_lds16(&Bg[(long)(bn + row) * K + kt + g * 8],
                     &Bs[buf][row * 32 + sck * 8]);
        }
        #pragma unroll
        for (int rr = 0; rr < 2; ++rr) {           // A: 2 DMAs
            int row = srow + rr * 64;
            int g   = sck ^ ((row >> 1) & 3);
            const short* src;
            if (MODE == 2) {
                int gr = bm + row;
                src = &Ag[((long)(gr >> 2)) * 640 +
                          ((gr & 3) + 1) * 128 + kt + g * 8];
            } else {
                src = &Ag[(long)(bm + row) * K + kt + g * 8];
            }
            gl_lds16(src, &As[buf][row * 32 + sck * 8]);
        }
    };

    const int rbase = lane & 15;
    const int cg    = lane >> 4;        // k-chunk 0..3
    const int ca    = (cg ^ ((rbase >> 1) & 3)) << 3;   // swizzled, shorts

    const int nk = K >> 5;              // >= 4 for all our shapes
    stage(0, 0);
    stage(1, 32);
    if (nk > 2) stage(2, 64);

    for (int i = 0; i < nk; ++i) {
        if (i + 2 < nk)
            asm volatile("s_waitcnt vmcnt(8)" ::: "memory");
        else if (i + 1 < nk)
            asm volatile("s_waitcnt vmcnt(4)" ::: "memory");
        else
            asm volatile("s_waitcnt vmcnt(0)" ::: "memory");
        __builtin_amdgcn_s_barrier();
        __builtin_amdgcn_sched_barrier(0);

        const int cur = i & 3;
        bf16x8 af[4], bfr[4];
        #pragma unroll
        for (int mt = 0; mt < 4; ++mt)
            af[mt] = *(const bf16x8*)
                &As[cur][(wm + mt * 16 + rbase) * 32 + ca];
        #pragma unroll
        for (int nt = 0; nt < 4; ++nt)
            bfr[nt] = *(const bf16x8*)
                &Bs[cur][(wn + nt * 16 + rbase) * 32 + ca];
        #pragma unroll
        for (int mt = 0; mt < 4; ++mt)
            #pragma unroll
            for (int nt = 0; nt < 4; ++nt)
                acc[mt][nt] = __builtin_amdgcn_mfma_f32_16x16x32_bf16(
                    af[mt], bfr[nt], acc[mt][nt], 0, 0, 0);

        if (i + 3 < nk) stage((i + 3) & 3, (i + 3) << 5);
    }

    // epilogue: C/D layout col = lane&15, row = (lane>>4)*4 + i
    const int col0 = lane & 15;
    const int row0 = (lane >> 4) * 4;
    #pragma unroll
    for (int nt = 0; nt < 4; ++nt) {
        int col = bn + wn + nt * 16 + col0;
        float s = 1.f, t = 0.f;
        if (EPI == 1 || EPI == 2) { s = (EPI == 1) ? S[col] : 1.f; t = T[col]; }
        #pragma unroll
        for (int mt = 0; mt < 4; ++mt) {
            #pragma unroll
            for (int i = 0; i < 4; ++i) {
                int row = bm + wm + mt * 16 + row0 + i;
                float v = acc[mt][nt][i];
                if (EPI == 3) {
                    // row = b*4 + jsl, jsl == i (bm,wm,mt*16,row0 all %4==0)
                    const bfloat* xsp = (const bfloat*)A;
                    bfloat* Pp = (bfloat*)C;
                    long b = row >> 2;
                    int pplist[4];
                    int npp;
                    if (i == 0)      { npp = 1; pplist[0] = 0; }
                    else if (i == 1) { npp = 2; pplist[0] = 1; pplist[1] = 4; }
                    else if (i == 2) { npp = 3; pplist[0] = 2; pplist[1] = 5; pplist[2] = 7; }
                    else             { npp = 4; pplist[0] = 3; pplist[1] = 6; pplist[2] = 8; pplist[3] = 9; }
                    #pragma unroll
                    for (int t2 = 0; t2 < npp; ++t2) {
                        int pp  = pplist[t2];
                        int isl = ISL[pp];
                        float xv = __bfloat162float(
                            xsp[b * 640 + isl * 128 + col]);
                        Pp[b * 1280 + pp * 128 + col] =
                            __float2bfloat16(xv * v);
                    }
                } else {
                    if (EPI == 1) v = fmaxf(v * s + t, 0.f);
                    if (EPI == 2) v = v + t;
                    if (F32OUT) ((float*)C)[(size_t)row * N + col] = v;
                    else ((bfloat*)C)[(size_t)row * N + col] = __float2bfloat16(v);
                }
            }
        }
    }
}

// ---------------------------------------------------------------- head
__global__ __launch_bounds__(256) void head_kernel(
    const bfloat* __restrict__ h2, const float* __restrict__ W3,
    const float* __restrict__ b3, float* __restrict__ out)
{
    int lane = threadIdx.x & 63;
    int row  = blockIdx.x * 4 + (threadIdx.x >> 6);
    float acc = 0.f;
    #pragma unroll
    for (int i = 0; i < 4; ++i)
        acc += __bfloat162float(h2[(size_t)row * 256 + i * 64 + lane]) *
               W3[i * 64 + lane];
    #pragma unroll
    for (int off = 32; off > 0; off >>= 1) acc += __shfl_down(acc, off, 64);
    if (lane == 0) {
        float l = acc + b3[0];
        out[row] = 1.f / (1.f + expf(-l));
    }
}

// ---------------------------------------------------------------- launch
extern "C" void kernel_launch(void* const* d_in, const int* in_sizes, int n_in,
                              void* d_out, int out_size, void* d_ws, size_t ws_size,
                              hipStream_t stream) {
    const int*   item_id = (const int*)  d_in[0];
    const float* d128    = (const float*)d_in[1];
    const int*   likes   = (const int*)  d_in[2];
    const int*   views   = (const int*)  d_in[3];
    const int*   seq     = (const int*)  d_in[4];
    const float* item_emb= (const float*)d_in[5];
    const float* cate_emb= (const float*)d_in[6];
    const float* mm_W    = (const float*)d_in[7];
    const float* mm_b    = (const float*)d_in[8];
    const float* ln_g    = (const float*)d_in[9];
    const float* ln_b    = (const float*)d_in[10];
    const float* se_W1   = (const float*)d_in[11];
    const float* se_b1   = (const float*)d_in[12];
    const float* se_W2   = (const float*)d_in[13];
    const float* se_b2   = (const float*)d_in[14];
    const float* bi_W    = (const float*)d_in[15];
    const float* W1      = (const float*)d_in[16];
    const float* b1      = (const float*)d_in[17];
    const float* bn1_g   = (const float*)d_in[18];
    const float* bn1_b   = (const float*)d_in[19];
    const float* bn1_rm  = (const float*)d_in[20];
    const float* bn1_rv  = (const float*)d_in[21];
    const float* W2      = (const float*)d_in[22];
    const float* b2      = (const float*)d_in[23];
    const float* bn2_g   = (const float*)d_in[24];
    const float* bn2_b   = (const float*)d_in[25];
    const float* bn2_rm  = (const float*)d_in[26];
    const float* bn2_rv  = (const float*)d_in[27];
    const float* W3      = (const float*)d_in[28];
    const float* b3      = (const float*)d_in[29];

    // --------- workspace (ws ~ 268MB per round-14 fill evidence) --------
    // fixed: W1t 1,966,080 | W2t 262,144 | bWt 32,768 | mmWb 32,768 |
    //        S1/T1 4,096 | S2/T2 2,048 | pad 512 = 2,300,416 B
    // itemb (optional): 91718*128*2 = 23,479,808 B
    // per-row 4864 B: xs 1280 | h1 1024 | P 2560. h2 aliases P (post-MLP1).
    const size_t fixed = 2300416;
    const size_t ITB   = 23479808;
    int CH; bool use_tb;
    if      (fixed + ITB + (size_t)16384 * 4864 <= ws_size) { CH = 16384; use_tb = true;  }
    else if (fixed + (size_t)16384 * 4864 <= ws_size)       { CH = 16384; use_tb = false; }
    else if (fixed + ITB + (size_t)8192 * 4864 <= ws_size)  { CH = 8192;  use_tb = true;  }
    else if (fixed + (size_t)8192 * 4864 <= ws_size)        { CH = 8192;  use_tb = false; }
    else if (fixed + ITB + (size_t)4096 * 4864 <= ws_size)  { CH = 4096;  use_tb = true;  }
    else if (fixed + (size_t)4096 * 4864 <= ws_size)        { CH = 4096;  use_tb = false; }
    else if (fixed + (size_t)2048 * 4864 <= ws_size)        { CH = 2048;  use_tb = false; }
    else                                                    { CH = 1024;  use_tb = false; }

    char* ws = (char*)d_ws;
    bfloat* W1t = (bfloat*)(ws);                 // 1,966,080
    bfloat* W2t = (bfloat*)(ws + 1966080);       //   262,144
    bfloat* bWt = (bfloat*)(ws + 2228224);       //    32,768
    bfloat* mmWb= (bfloat*)(ws + 2260992);       //    32,768 ([k][e] cast)
    float*  S1  = (float*) (ws + 2293760);       //     2,048
    float*  T1  = (float*) (ws + 2295808);       //     2,048
    float*  S2  = (float*) (ws + 2297856);       //     1,024
    float*  T2  = (float*) (ws + 2298880);       //     1,024
    bfloat* itemb = (bfloat*)(ws + fixed);       // ITB (if use_tb)
    char*   cb  = ws + fixed + (use_tb ? ITB : 0);
    bfloat* xs  = (bfloat*)(cb);                            // CH*1280 B
    bfloat* h1  = (bfloat*)(cb + (size_t)CH * 1280);        // CH*1024 B
    bfloat* P   = (bfloat*)(cb + (size_t)CH * 2304);        // CH*2560 B
    bfloat* h2  = (bfloat*)P;                               // alias (post-MLP1)

    // single fused pre-pass: W1c tiles + small prep + (optional) cvt_emb
    {
        int nblk = 884 + (use_tb ? (91718 * 128 / 8 + 255) / 256 : 0);
        mega_prep<<<nblk, 256, 0, stream>>>(
            W1, W1t, W2, bi_W, mm_W, W2t, bWt, mmWb,
            b1, bn1_g, bn1_b, bn1_rm, bn1_rv,
            b2, bn2_g, bn2_b, bn2_rm, bn2_rv,
            S1, T1, S2, T2,
            item_emb, use_tb ? itemb : nullptr);
    }

    for (int off = 0; off < B_SZ; off += CH) {
        // feat (mm fused in-kernel: broadcast-k dot, coalesced mmWb reads)
        if (use_tb)
            feat_kernel<1><<<CH / 2, 256, 0, stream>>>(
                item_id + off, likes + off, views + off,
                seq + (size_t)off * HIST_L, itemb, cate_emb,
                d128 + (size_t)off * 128, mmWb, mm_b,
                ln_g, ln_b, se_W1, se_b1, se_W2, se_b2, xs);
        else
            feat_kernel<0><<<CH / 2, 256, 0, stream>>>(
                item_id + off, likes + off, views + off,
                seq + (size_t)off * HIST_L, item_emb, cate_emb,
                d128 + (size_t)off * 128, mmWb, mm_b,
                ln_g, ln_b, se_W1, se_b1, se_W2, se_b2, xs);

        // xw GEMM + fused pair epilogue: writes P directly.
        dim3 gxw(CH * 4 / 128, 1);
        gemm_bt<2, 3, 0><<<gxw, 256, 0, stream>>>(
            xs, nullptr, bWt, P, CH * 4, 128, 128, nullptr, nullptr);

        // h1 = relu(BN1([xs|P] @ W1t^T)): K = 1920 (r19 kernel)
        dim3 g1(CH / 256, 4);
        gemm_mlp1<<<g1, 256, 147456, stream>>>(
            xs, P, W1t, h1, CH, 512, 1920, S1, T1);

        // h2 = relu(BN2(h1 @ W2)): K = 512  (h2 overwrites P - dead)
        dim3 g2(CH / 128, 2);
        gemm_bt<0, 1, 0><<<g2, 256, 0, stream>>>(
            h1, nullptr, W2t, h2, CH, 256, 512, S2, T2);

        head_kernel<<<CH / 4, 256, 0, stream>>>(h2, W3, b3, (float*)d_out + off);
    }
}

// Round 15
// 271.613 us; speedup vs baseline: 1.1625x; 1.0734x over previous
//
#include <hip/hip_runtime.h>
#include <hip/hip_bf16.h>

typedef __hip_bfloat16 bfloat;
typedef __bf16 bf16x8 __attribute__((ext_vector_type(8)));
typedef float f32x4 __attribute__((ext_vector_type(4)));

#define B_SZ   16384
#define E_DIM  128
#define HIST_L 50

// DTYPE MAP: inputs fp32, output fp32, internal bf16 for MFMA.
// ROUND 20 pm: mm-dot fusion (gather layout) = feat 97.7us. REGRESSED.
// ROUND 21 pm: coalesced-e dot = feat 68.4us, VALUBusy 54% -> dot is
//   ~35us of UNHIDDEN VALU. Separate MFMA mm GEMM measured ~8us. Fusion
//   concept FALSIFIED by two measurements -> closed.
// ROUND 22: revert mm to separate GEMM, keep session wins:
//   - mm = gemm_bt<0,2,1> pure-DMA MODE 0 (no per-tile lgkmcnt drain):
//     mega_prep gains a d128->bf16 cast section (d128b, 4MB fixed) so mm
//     staging is 100% global_load_lds.
//   - feat reverts to precomputed fp32 mm (aliases P front, dead before
//     xw-GEMM writes P).
//   - mega_prep, bf16 item table, r19 MLP1, r18 gemm_bt unchanged.
// ROUND 23-26: bench FAILED FOUR TIMES with GPUAcquisitionTimeout (broker
//   capacity, not kernel error). Resubmitting UNCHANGED — no blind edits
//   without a measurement. Prediction: total ~268-274us.

// pairs (I,J), pp=0..9: (1,2)(1,3)(1,4)(1,5)(2,3)(2,4)(2,5)(3,4)(3,5)(4,5)
// xs slot = I-1 (ISL), xw row = J-2 (groups by jsl below).
__device__ __constant__ int ISL[10] = {0,0,0,0,1,1,1,2,2,3};

__device__ __forceinline__ void gl_lds16(const void* g, void* l) {
    __builtin_amdgcn_global_load_lds(
        (const __attribute__((address_space(1))) unsigned int*)g,
        (__attribute__((address_space(3))) unsigned int*)l, 16, 0, 0);
}

// ---------------------------------------------------------------- features
// 256 threads = 2 batch rows per block. mm (post-bias fp32) precomputed.
// TB=1: item table is bf16 (itemb, row0 zeroed). TB=0: fp32 item_emb.
template<int TB>
__global__ __launch_bounds__(256) void feat_kernel(
    const int* __restrict__ item_id,
    const int* __restrict__ likes, const int* __restrict__ views,
    const int* __restrict__ seq,
    const void* __restrict__ item_tab, const float* __restrict__ cate_emb,
    const float* __restrict__ mm,
    const float* __restrict__ ln_g, const float* __restrict__ ln_b,
    const float* __restrict__ se_W1, const float* __restrict__ se_b1,
    const float* __restrict__ se_W2, const float* __restrict__ se_b2,
    bfloat* __restrict__ xs)
{
    const int tid = threadIdx.x;
    const int r   = tid >> 7;            // sub-row 0/1
    const int e   = tid & 127;
    const int b   = blockIdx.x * 2 + r;
    const int w   = tid >> 6;            // wave 0..3 (row = w>>1)

    __shared__ float redh[2][4][128];
    __shared__ int   seq_s[2][64];
    __shared__ float lnred[4], lnred2[4];
    __shared__ float zred[5][4];
    __shared__ float wsh[2][6];
    __shared__ int   cnt_s[2];

    if (e < 64) seq_s[r][e] = (e < HIST_L) ? seq[(size_t)b * HIST_L + e] : 0;
    __syncthreads();

    // long-latency gathers first
    const int iid = item_id[b];
    const float like_v = cate_emb[likes[b] * 128 + e];
    const float view_v = cate_emb[views[b] * 128 + e];
    float item_v;
    if (TB) {
        const bfloat* tb = (const bfloat*)item_tab;
        item_v = __bfloat162float(tb[(size_t)iid * 128 + e]);  // row0 zeroed
    } else {
        const float* tf = (const float*)item_tab;
        float raw = tf[(size_t)iid * 128 + e];
        item_v = iid ? raw : 0.f;
    }
    const float acc = mm[(size_t)b * 128 + e];   // bias already added

    const int q   = e >> 5;
    const int l32 = e & 31;
    float4 hs = make_float4(0.f, 0.f, 0.f, 0.f);
    if (TB) {
        const ushort* tb = (const ushort*)item_tab;
        #pragma unroll
        for (int g = 0; g < 13; ++g) {
            int s = seq_s[r][g * 4 + q];
            ushort4 v = *(const ushort4*)&tb[(size_t)s * 128 + l32 * 4];
            hs.x += __bfloat162float(__ushort_as_bfloat16(v.x));
            hs.y += __bfloat162float(__ushort_as_bfloat16(v.y));
            hs.z += __bfloat162float(__ushort_as_bfloat16(v.z));
            hs.w += __bfloat162float(__ushort_as_bfloat16(v.w));
        }
    } else {
        const float* tf = (const float*)item_tab;
        #pragma unroll
        for (int g = 0; g < 13; ++g) {
            int s = seq_s[r][g * 4 + q];
            const float4 v = *(const float4*)&tf[(size_t)s * 128 + l32 * 4];
            float m = (s != 0) ? 1.f : 0.f;
            hs.x = fmaf(v.x, m, hs.x);
            hs.y = fmaf(v.y, m, hs.y);
            hs.z = fmaf(v.z, m, hs.z);
            hs.w = fmaf(v.w, m, hs.w);
        }
    }

    // LayerNorm reductions (per 2-wave row)
    {
        float v = acc;
        #pragma unroll
        for (int off = 32; off > 0; off >>= 1) v += __shfl_down(v, off, 64);
        if ((tid & 63) == 0) lnred[w] = v;
    }
    __syncthreads();
    const float mu = (lnred[2 * r] + lnred[2 * r + 1]) * (1.f / 128.f);
    const float d  = acc - mu;
    {
        float v = d * d;
        #pragma unroll
        for (int off = 32; off > 0; off >>= 1) v += __shfl_down(v, off, 64);
        if ((tid & 63) == 0) lnred2[w] = v;
    }
    redh[r][q][l32 * 4 + 0] = hs.x;
    redh[r][q][l32 * 4 + 1] = hs.y;
    redh[r][q][l32 * 4 + 2] = hs.z;
    redh[r][q][l32 * 4 + 3] = hs.w;
    if ((w & 1) == 0 && e < 64) {       // first wave of each row
        bool valid = (e < HIST_L) && (seq_s[r][e] != 0);
        unsigned long long m = __ballot(valid);
        if (e == 0) cnt_s[r] = (int)__popcll(m);
    }
    __syncthreads();
    const float var = (lnred2[2 * r] + lnred2[2 * r + 1]) * (1.f / 128.f);
    float xmm = d * rsqrtf(var + 1e-5f) * ln_g[e] + ln_b[e];
    xmm = fmaxf(xmm, 0.f);

    const int cnt = cnt_s[r] > 0 ? cnt_s[r] : 1;
    const float hist_v = (redh[r][0][e] + redh[r][1][e] +
                          redh[r][2][e] + redh[r][3][e]) / (float)cnt;

    // SENet z means: 5 sums, one barrier
    {
        float s1 = like_v, s2 = view_v, s3 = item_v, s4 = xmm, s5 = hist_v;
        #pragma unroll
        for (int off = 32; off > 0; off >>= 1) {
            s1 += __shfl_down(s1, off, 64);
            s2 += __shfl_down(s2, off, 64);
            s3 += __shfl_down(s3, off, 64);
            s4 += __shfl_down(s4, off, 64);
            s5 += __shfl_down(s5, off, 64);
        }
        if ((tid & 63) == 0) {
            zred[0][w] = s1; zred[1][w] = s2; zred[2][w] = s3;
            zred[3][w] = s4; zred[4][w] = s5;
        }
    }
    __syncthreads();

    if (e == 0) {
        float z[6];
        z[0] = 0.f;
        #pragma unroll
        for (int f = 1; f < 6; ++f)
            z[f] = (zred[f - 1][2 * r] + zred[f - 1][2 * r + 1]) * (1.f / 128.f);
        float a[3];
        #pragma unroll
        for (int j = 0; j < 3; ++j) {
            float s = se_b1[j];
            #pragma unroll
            for (int f = 0; f < 6; ++f) s += z[f] * se_W1[f * 3 + j];
            a[j] = fmaxf(s, 0.f);
        }
        #pragma unroll
        for (int f = 0; f < 6; ++f) {
            float s = se_b2[f];
            #pragma unroll
            for (int j = 0; j < 3; ++j) s += a[j] * se_W2[j * 6 + f];
            wsh[r][f] = 1.f / (1.f + expf(-s));
        }
    }
    __syncthreads();

    bfloat* xrow = xs + (size_t)b * 640;      // fields 1..5 at slots 0..4
    xrow[0 * 128 + e] = __float2bfloat16(like_v * wsh[r][1]);
    xrow[1 * 128 + e] = __float2bfloat16(view_v * wsh[r][2]);
    xrow[2 * 128 + e] = __float2bfloat16(item_v * wsh[r][3]);
    xrow[3 * 128 + e] = __float2bfloat16(xmm    * wsh[r][4]);
    xrow[4 * 128 + e] = __float2bfloat16(hist_v * wsh[r][5]);
}

// ---------------------------------------------------------------- pre-pass
// ONE kernel, partitioned by blockIdx:
//   blocks 0..239     : W1 compact transpose, LDS-tiled (30 x 8 tiles)
//   blocks 240..883   : W2t/bWt/mmWt transposes + BN folding + Tmm
//   blocks 884..1907  : d128 fp32 -> bf16 cast (all B_SZ rows)
//   blocks 1908..     : item_emb fp32 -> bf16 table (row 0 zeroed)
__global__ __launch_bounds__(256) void mega_prep(
    const float* __restrict__ W1, bfloat* __restrict__ W1t,
    const float* __restrict__ W2, const float* __restrict__ bi_W,
    const float* __restrict__ mm_W,
    bfloat* __restrict__ W2t, bfloat* __restrict__ bWt,
    bfloat* __restrict__ mmWt,
    const float* __restrict__ lb1, const float* __restrict__ g1,
    const float* __restrict__ bb1, const float* __restrict__ rm1,
    const float* __restrict__ rv1,
    const float* __restrict__ lb2, const float* __restrict__ g2,
    const float* __restrict__ bb2, const float* __restrict__ rm2,
    const float* __restrict__ rv2,
    const float* __restrict__ mm_b,
    float* __restrict__ S1, float* __restrict__ T1,
    float* __restrict__ S2, float* __restrict__ T2,
    float* __restrict__ Tmm,
    const float* __restrict__ d128, bfloat* __restrict__ d128b,
    const float* __restrict__ item_emb, bfloat* __restrict__ itemb)
{
    const int blk = blockIdx.x;
    const int tid = threadIdx.x;
    if (blk < 240) {
        // W1t[n][kk] = W1[orig(kk)][n], orig = kk + (kk<640?128:768)
        __shared__ float t[64][65];
        const int kk0 = (blk % 30) * 64, n0 = (blk / 30) * 64;
        const int j = tid & 63;
        #pragma unroll
        for (int p = 0; p < 16; ++p) {
            int i = (tid >> 6) + p * 4;
            int kk = kk0 + i;
            int orig = kk + (kk < 640 ? 128 : 768);
            t[i][j] = W1[(size_t)orig * 512 + n0 + j];
        }
        __syncthreads();
        #pragma unroll
        for (int p = 0; p < 16; ++p) {
            int i = (tid >> 6) + p * 4;
            W1t[(size_t)(n0 + i) * 1920 + kk0 + j] = __float2bfloat16(t[j][i]);
        }
    } else if (blk < 884) {
        int idx = (blk - 240) * 256 + tid;
        if (idx < 131072) {                    // W2t: (512,256) -> (256,512)
            int k = idx >> 8, n = idx & 255;
            W2t[(size_t)n * 512 + k] = __float2bfloat16(W2[idx]);
        } else if (idx < 147456) {             // bWt: 128x128 transpose
            int t2 = idx - 131072;
            int k = t2 >> 7, n = t2 & 127;
            bWt[n * 128 + k] = __float2bfloat16(bi_W[t2]);
        } else if (idx < 163840) {             // mmWt: 128x128 transpose
            int t2 = idx - 147456;
            int k = t2 >> 7, n = t2 & 127;
            mmWt[n * 128 + k] = __float2bfloat16(mm_W[t2]);
        } else if (idx < 164352) {             // S1/T1
            int j = idx - 163840;
            float s = g1[j] * rsqrtf(rv1[j] + 1e-5f);
            S1[j] = s;
            T1[j] = (lb1[j] - rm1[j]) * s + bb1[j];
        } else if (idx < 164608) {             // S2/T2
            int j = idx - 164352;
            float s = g2[j] * rsqrtf(rv2[j] + 1e-5f);
            S2[j] = s;
            T2[j] = (lb2[j] - rm2[j]) * s + bb2[j];
        } else if (idx < 164736) {             // Tmm
            Tmm[idx - 164608] = mm_b[idx - 164608];
        }
    } else if (blk < 1908) {
        // d128 cast: 16384*128/8 = 262144 chunks over 1024 blocks
        int idx = (blk - 884) * 256 + tid;
        float4 f0 = ((const float4*)d128)[idx * 2];
        float4 f1 = ((const float4*)d128)[idx * 2 + 1];
        union { bf16x8 v; unsigned short s[8]; } u;
        u.s[0] = __bfloat16_as_ushort(__float2bfloat16(f0.x));
        u.s[1] = __bfloat16_as_ushort(__float2bfloat16(f0.y));
        u.s[2] = __bfloat16_as_ushort(__float2bfloat16(f0.z));
        u.s[3] = __bfloat16_as_ushort(__float2bfloat16(f0.w));
        u.s[4] = __bfloat16_as_ushort(__float2bfloat16(f1.x));
        u.s[5] = __bfloat16_as_ushort(__float2bfloat16(f1.y));
        u.s[6] = __bfloat16_as_ushort(__float2bfloat16(f1.z));
        u.s[7] = __bfloat16_as_ushort(__float2bfloat16(f1.w));
        ((bf16x8*)d128b)[idx] = u.v;
    } else {
        if (itemb == nullptr) return;
        const int n8 = 91718 * 128 / 8;
        int idx = (blk - 1908) * 256 + tid;
        if (idx >= n8) return;
        if (idx < 16) {                        // row 0 zeroed (padding_idx)
            union { bf16x8 v; unsigned short s[8]; } z;
            #pragma unroll
            for (int i = 0; i < 8; ++i) z.s[i] = 0;
            ((bf16x8*)itemb)[idx] = z.v;
            return;
        }
        float4 f0 = ((const float4*)item_emb)[idx * 2];
        float4 f1 = ((const float4*)item_emb)[idx * 2 + 1];
        union { bf16x8 v; unsigned short s[8]; } u;
        u.s[0] = __bfloat16_as_ushort(__float2bfloat16(f0.x));
        u.s[1] = __bfloat16_as_ushort(__float2bfloat16(f0.y));
        u.s[2] = __bfloat16_as_ushort(__float2bfloat16(f0.z));
        u.s[3] = __bfloat16_as_ushort(__float2bfloat16(f0.w));
        u.s[4] = __bfloat16_as_ushort(__float2bfloat16(f1.x));
        u.s[5] = __bfloat16_as_ushort(__float2bfloat16(f1.y));
        u.s[6] = __bfloat16_as_ushort(__float2bfloat16(f1.z));
        u.s[7] = __bfloat16_as_ushort(__float2bfloat16(f1.w));
        ((bf16x8*)itemb)[idx] = u.v;
    }
}

// ---------------------------------------------------------------- MLP1 GEMM
// (r19, unchanged — measured 48.3us.)
// h1 = relu(BN1([xs|P] @ W1t^T)). Tile 256x128, BK=64, 1 block/CU.
// 3 dynamic-LDS buffers x 48KB; 4 waves (1/SIMD), 64 MFMA + 24 ds_read
// per K-tile per wave; counted vmcnt(12) pipeline; swizzle c^(row&7).
__global__ __launch_bounds__(256, 1) void gemm_mlp1(
    const bfloat* __restrict__ Axs, const bfloat* __restrict__ Ap,
    const bfloat* __restrict__ Bt, bfloat* __restrict__ C,
    int M, int N, int K,
    const float* __restrict__ S, const float* __restrict__ T)
{
    extern __shared__ __align__(16) short smem[];   // 3 x 24576 shorts

    const int tid  = threadIdx.x;
    const int bm   = blockIdx.x * 256;
    const int bn   = blockIdx.y * 128;
    const int wave = tid >> 6;
    const int lane = tid & 63;
    const int wm   = (wave >> 1) * 128;
    const int wn   = (wave & 1) * 64;

    const short* Ag  = (const short*)Axs;
    const short* A2g = (const short*)Ap;
    const short* Bg  = (const short*)Bt;

    f32x4 acc[8][4];
    #pragma unroll
    for (int i = 0; i < 8; ++i)
        #pragma unroll
        for (int j = 0; j < 4; ++j)
            acc[i][j] = (f32x4){0.f, 0.f, 0.f, 0.f};

    const int l8  = lane >> 3;          // == staged row & 7
    const int gch = (lane & 7) ^ l8;    // global chunk for this lane

    auto stage = [&](int buf, int kt) {
        short* Ab = smem + buf * 24576;
        short* Bb = Ab + 16384;
        #pragma unroll
        for (int d = 0; d < 4; ++d) {              // B: 4 DMAs
            int seg = wave * 4 + d;
            int row = seg * 8 + l8;
            gl_lds16(&Bg[(long)(bn + row) * K + kt + gch * 8],
                     &Bb[seg * 512 + lane * 8]);
        }
        #pragma unroll
        for (int d = 0; d < 8; ++d) {              // A: 8 DMAs
            int seg = wave * 8 + d;
            int row = seg * 8 + l8;
            long rb = (long)(bm + row);
            const short* src = (kt < 640)
                ? &Ag [rb * 640  + kt + gch * 8]
                : &A2g[rb * 1280 + (kt - 640) + gch * 8];
            gl_lds16(src, &Ab[seg * 512 + lane * 8]);
        }
    };

    const int rbase = lane & 15;
    const int rsw   = rbase & 7;

    const int nk = K >> 6;              // 30
    stage(0, 0);
    stage(1, 64);

    for (int i = 0; i < nk; ++i) {
        if (i + 1 < nk) asm volatile("s_waitcnt vmcnt(12)" ::: "memory");
        else            asm volatile("s_waitcnt vmcnt(0)" ::: "memory");
        __builtin_amdgcn_s_barrier();
        __builtin_amdgcn_sched_barrier(0);

        if (i + 2 < nk) stage((i + 2) % 3, (i + 2) << 6);

        const short* Ab = smem + (i % 3) * 24576;
        const short* Bb = Ab + 16384;
        #pragma unroll
        for (int h = 0; h < 2; ++h) {
            const int cg = h * 4 + (lane >> 4);     // global chunk 0..7
            const int ca = (cg ^ rsw) << 3;         // swizzled, shorts
            bf16x8 af[8], bfr[4];
            #pragma unroll
            for (int mt = 0; mt < 8; ++mt)
                af[mt] = *(const bf16x8*)
                    &Ab[(wm + mt * 16 + rbase) * 64 + ca];
            #pragma unroll
            for (int nt = 0; nt < 4; ++nt)
                bfr[nt] = *(const bf16x8*)
                    &Bb[(wn + nt * 16 + rbase) * 64 + ca];
            #pragma unroll
            for (int mt = 0; mt < 8; ++mt)
                #pragma unroll
                for (int nt = 0; nt < 4; ++nt)
                    acc[mt][nt] = __builtin_amdgcn_mfma_f32_16x16x32_bf16(
                        af[mt], bfr[nt], acc[mt][nt], 0, 0, 0);
        }
    }

    // epilogue: relu(acc*S+T); C/D layout col = lane&15, row = (lane>>4)*4+i
    const int col0 = lane & 15;
    const int row0 = (lane >> 4) * 4;
    #pragma unroll
    for (int nt = 0; nt < 4; ++nt) {
        int col = bn + wn + nt * 16 + col0;
        float s = S[col], t = T[col];
        #pragma unroll
        for (int mt = 0; mt < 8; ++mt) {
            #pragma unroll
            for (int i = 0; i < 4; ++i) {
                int row = bm + wm + mt * 16 + row0 + i;
                float v = fmaxf(acc[mt][nt][i] * s + t, 0.f);
                C[(size_t)row * N + col] = __float2bfloat16(v);
            }
        }
    }
}

// ---------------------------------------------------------------- MFMA GEMM
// (r18 template — used for mm (MODE 0/EPI 2/F32OUT), xw (MODE 2/EPI 3),
// MLP2 (MODE 0/EPI 1).)
// Tile 128x128, BK=32, depth-3 counted-vmcnt pipeline over 4 LDS buffers.
template<int MODE, int EPI, int F32OUT>
__global__ __launch_bounds__(256, 2) void gemm_bt(
    const void* __restrict__ A, const bfloat* __restrict__ A2,
    const bfloat* __restrict__ Bt, void* __restrict__ C,
    int M, int N, int K,
    const float* __restrict__ S, const float* __restrict__ T)
{
    __shared__ __align__(16) short As[4][128 * 32];
    __shared__ __align__(16) short Bs[4][128 * 32];

    const int tid  = threadIdx.x;
    const int bm   = blockIdx.x * 128;
    const int bn   = blockIdx.y * 128;
    const int wave = tid >> 6;
    const int lane = tid & 63;
    const int wm   = (wave >> 1) * 64;
    const int wn   = (wave & 1) * 64;

    const short* Ag  = (const short*)A;
    const short* Bg  = (const short*)Bt;

    f32x4 acc[4][4];
    #pragma unroll
    for (int i = 0; i < 4; ++i)
        #pragma unroll
        for (int j = 0; j < 4; ++j)
            acc[i][j] = (f32x4){0.f, 0.f, 0.f, 0.f};

    const int srow = tid >> 2;          // 0..63 (staging row within pass)
    const int sck  = tid & 3;           // dest 16B chunk within 64B row

    auto stage = [&](int buf, int kt) {
        #pragma unroll
        for (int rr = 0; rr < 2; ++rr) {           // B: 2 DMAs
            int row = srow + rr * 64;
            int g   = sck ^ ((row >> 1) & 3);      // swizzled global chunk
            gl_lds16(&Bg[(long)(bn + row) * K + kt + g * 8],
                     &Bs[buf][row * 32 + sck * 8]);
        }
        #pragma unroll
        for (int rr = 0; rr < 2; ++rr) {           // A: 2 DMAs
            int row = srow + rr * 64;
            int g   = sck ^ ((row >> 1) & 3);
            const short* src;
            if (MODE == 2) {
                int gr = bm + row;
                src = &Ag[((long)(gr >> 2)) * 640 +
                          ((gr & 3) + 1) * 128 + kt + g * 8];
            } else {
                src = &Ag[(long)(bm + row) * K + kt + g * 8];
            }
            gl_lds16(src, &As[buf][row * 32 + sck * 8]);
        }
    };

    const int rbase = lane & 15;
    const int cg    = lane >> 4;        // k-chunk 0..3
    const int ca    = (cg ^ ((rbase >> 1) & 3)) << 3;   // swizzled, shorts

    const int nk = K >> 5;              // >= 4 for all our shapes
    stage(0, 0);
    stage(1, 32);
    if (nk > 2) stage(2, 64);

    for (int i = 0; i < nk; ++i) {
        if (i + 2 < nk)
            asm volatile("s_waitcnt vmcnt(8)" ::: "memory");
        else if (i + 1 < nk)
            asm volatile("s_waitcnt vmcnt(4)" ::: "memory");
        else
            asm volatile("s_waitcnt vmcnt(0)" ::: "memory");
        __builtin_amdgcn_s_barrier();
        __builtin_amdgcn_sched_barrier(0);

        const int cur = i & 3;
        bf16x8 af[4], bfr[4];
        #pragma unroll
        for (int mt = 0; mt < 4; ++mt)
            af[mt] = *(const bf16x8*)
                &As[cur][(wm + mt * 16 + rbase) * 32 + ca];
        #pragma unroll
        for (int nt = 0; nt < 4; ++nt)
            bfr[nt] = *(const bf16x8*)
                &Bs[cur][(wn + nt * 16 + rbase) * 32 + ca];
        #pragma unroll
        for (int mt = 0; mt < 4; ++mt)
            #pragma unroll
            for (int nt = 0; nt < 4; ++nt)
                acc[mt][nt] = __builtin_amdgcn_mfma_f32_16x16x32_bf16(
                    af[mt], bfr[nt], acc[mt][nt], 0, 0, 0);

        if (i + 3 < nk) stage((i + 3) & 3, (i + 3) << 5);
    }

    // epilogue: C/D layout col = lane&15, row = (lane>>4)*4 + i
    const int col0 = lane & 15;
    const int row0 = (lane >> 4) * 4;
    #pragma unroll
    for (int nt = 0; nt < 4; ++nt) {
        int col = bn + wn + nt * 16 + col0;
        float s = 1.f, t = 0.f;
        if (EPI == 1 || EPI == 2) { s = (EPI == 1) ? S[col] : 1.f; t = T[col]; }
        #pragma unroll
        for (int mt = 0; mt < 4; ++mt) {
            #pragma unroll
            for (int i = 0; i < 4; ++i) {
                int row = bm + wm + mt * 16 + row0 + i;
                float v = acc[mt][nt][i];
                if (EPI == 3) {
                    // row = b*4 + jsl, jsl == i (bm,wm,mt*16,row0 all %4==0)
                    const bfloat* xsp = (const bfloat*)A;
                    bfloat* Pp = (bfloat*)C;
                    long b = row >> 2;
                    int pplist[4];
                    int npp;
                    if (i == 0)      { npp = 1; pplist[0] = 0; }
                    else if (i == 1) { npp = 2; pplist[0] = 1; pplist[1] = 4; }
                    else if (i == 2) { npp = 3; pplist[0] = 2; pplist[1] = 5; pplist[2] = 7; }
                    else             { npp = 4; pplist[0] = 3; pplist[1] = 6; pplist[2] = 8; pplist[3] = 9; }
                    #pragma unroll
                    for (int t2 = 0; t2 < npp; ++t2) {
                        int pp  = pplist[t2];
                        int isl = ISL[pp];
                        float xv = __bfloat162float(
                            xsp[b * 640 + isl * 128 + col]);
                        Pp[b * 1280 + pp * 128 + col] =
                            __float2bfloat16(xv * v);
                    }
                } else {
                    if (EPI == 1) v = fmaxf(v * s + t, 0.f);
                    if (EPI == 2) v = v + t;
                    if (F32OUT) ((float*)C)[(size_t)row * N + col] = v;
                    else ((bfloat*)C)[(size_t)row * N + col] = __float2bfloat16(v);
                }
            }
        }
    }
}

// ---------------------------------------------------------------- head
__global__ __launch_bounds__(256) void head_kernel(
    const bfloat* __restrict__ h2, const float* __restrict__ W3,
    const float* __restrict__ b3, float* __restrict__ out)
{
    int lane = threadIdx.x & 63;
    int row  = blockIdx.x * 4 + (threadIdx.x >> 6);
    float acc = 0.f;
    #pragma unroll
    for (int i = 0; i < 4; ++i)
        acc += __bfloat162float(h2[(size_t)row * 256 + i * 64 + lane]) *
               W3[i * 64 + lane];
    #pragma unroll
    for (int off = 32; off > 0; off >>= 1) acc += __shfl_down(acc, off, 64);
    if (lane == 0) {
        float l = acc + b3[0];
        out[row] = 1.f / (1.f + expf(-l));
    }
}

// ---------------------------------------------------------------- launch
extern "C" void kernel_launch(void* const* d_in, const int* in_sizes, int n_in,
                              void* d_out, int out_size, void* d_ws, size_t ws_size,
                              hipStream_t stream) {
    const int*   item_id = (const int*)  d_in[0];
    const float* d128    = (const float*)d_in[1];
    const int*   likes   = (const int*)  d_in[2];
    const int*   views   = (const int*)  d_in[3];
    const int*   seq     = (const int*)  d_in[4];
    const float* item_emb= (const float*)d_in[5];
    const float* cate_emb= (const float*)d_in[6];
    const float* mm_W    = (const float*)d_in[7];
    const float* mm_b    = (const float*)d_in[8];
    const float* ln_g    = (const float*)d_in[9];
    const float* ln_b    = (const float*)d_in[10];
    const float* se_W1   = (const float*)d_in[11];
    const float* se_b1   = (const float*)d_in[12];
    const float* se_W2   = (const float*)d_in[13];
    const float* se_b2   = (const float*)d_in[14];
    const float* bi_W    = (const float*)d_in[15];
    const float* W1      = (const float*)d_in[16];
    const float* b1      = (const float*)d_in[17];
    const float* bn1_g   = (const float*)d_in[18];
    const float* bn1_b   = (const float*)d_in[19];
    const float* bn1_rm  = (const float*)d_in[20];
    const float* bn1_rv  = (const float*)d_in[21];
    const float* W2      = (const float*)d_in[22];
    const float* b2      = (const float*)d_in[23];
    const float* bn2_g   = (const float*)d_in[24];
    const float* bn2_b   = (const float*)d_in[25];
    const float* bn2_rm  = (const float*)d_in[26];
    const float* bn2_rv  = (const float*)d_in[27];
    const float* W3      = (const float*)d_in[28];
    const float* b3      = (const float*)d_in[29];

    // --------- workspace (ws ~ 268MB per round-14 fill evidence) --------
    // fixed: W1t 1,966,080 | W2t 262,144 | bWt 32,768 | mmWt 32,768 |
    //        S1/T1 4,096 | S2/T2 2,048 | Tmm 512 = 2,300,416 B
    // d128b: 16384*128*2 = 4,194,304 B (always, right after fixed)
    // itemb (optional): 91718*128*2 = 23,479,808 B
    // per-row 4864 B: xs 1280 | h1 1024 | P 2560.  mm f32 (512B/row)
    //   aliases P front (dead before xw-GEMM writes P); h2 aliases P.
    const size_t fixed = 2300416;
    const size_t DB    = 4194304;
    const size_t ITB   = 23479808;
    int CH; bool use_tb;
    if      (fixed + DB + ITB + (size_t)16384 * 4864 <= ws_size) { CH = 16384; use_tb = true;  }
    else if (fixed + DB + (size_t)16384 * 4864 <= ws_size)       { CH = 16384; use_tb = false; }
    else if (fixed + DB + ITB + (size_t)8192 * 4864 <= ws_size)  { CH = 8192;  use_tb = true;  }
    else if (fixed + DB + (size_t)8192 * 4864 <= ws_size)        { CH = 8192;  use_tb = false; }
    else if (fixed + DB + ITB + (size_t)4096 * 4864 <= ws_size)  { CH = 4096;  use_tb = true;  }
    else if (fixed + DB + (size_t)4096 * 4864 <= ws_size)        { CH = 4096;  use_tb = false; }
    else if (fixed + DB + (size_t)2048 * 4864 <= ws_size)        { CH = 2048;  use_tb = false; }
    else                                                         { CH = 1024;  use_tb = false; }

    char* ws = (char*)d_ws;
    bfloat* W1t = (bfloat*)(ws);                 // 1,966,080
    bfloat* W2t = (bfloat*)(ws + 1966080);       //   262,144
    bfloat* bWt = (bfloat*)(ws + 2228224);       //    32,768
    bfloat* mmWt= (bfloat*)(ws + 2260992);       //    32,768
    float*  S1  = (float*) (ws + 2293760);       //     2,048
    float*  T1  = (float*) (ws + 2295808);       //     2,048
    float*  S2  = (float*) (ws + 2297856);       //     1,024
    float*  T2  = (float*) (ws + 2298880);       //     1,024
    float*  Tmm = (float*) (ws + 2299904);       //       512 -> 2,300,416
    bfloat* d128b = (bfloat*)(ws + fixed);       // 4,194,304 (all rows)
    bfloat* itemb = (bfloat*)(ws + fixed + DB);  // ITB (if use_tb)
    char*   cb  = ws + fixed + DB + (use_tb ? ITB : 0);
    bfloat* xs  = (bfloat*)(cb);                            // CH*1280 B
    bfloat* h1  = (bfloat*)(cb + (size_t)CH * 1280);        // CH*1024 B
    bfloat* P   = (bfloat*)(cb + (size_t)CH * 2304);        // CH*2560 B
    float*  mm  = (float*)P;                                // CH*512 B (pre-xw)
    bfloat* h2  = (bfloat*)P;                               // alias (post-MLP1)

    // single fused pre-pass: W1c + small prep + d128 cast + (opt) cvt_emb
    {
        int nblk = 1908 + (use_tb ? (91718 * 128 / 8 + 255) / 256 : 0);
        mega_prep<<<nblk, 256, 0, stream>>>(
            W1, W1t, W2, bi_W, mm_W, W2t, bWt, mmWt,
            b1, bn1_g, bn1_b, bn1_rm, bn1_rv,
            b2, bn2_g, bn2_b, bn2_rm, bn2_rv,
            mm_b, S1, T1, S2, T2, Tmm,
            d128, d128b,
            item_emb, use_tb ? itemb : nullptr);
    }

    for (int off = 0; off < B_SZ; off += CH) {
        // mm = d128b @ mmWt^T + mm_b  (pure-DMA MODE 0; fp32 out to P
        // front, consumed by feat before xw-GEMM writes P)
        dim3 gmm(CH / 128, 1);
        gemm_bt<0, 2, 1><<<gmm, 256, 0, stream>>>(
            d128b + (size_t)off * 128, nullptr, mmWt, mm,
            CH, 128, 128, nullptr, Tmm);

        if (use_tb)
            feat_kernel<1><<<CH / 2, 256, 0, stream>>>(
                item_id + off, likes + off, views + off,
                seq + (size_t)off * HIST_L, itemb, cate_emb, mm,
                ln_g, ln_b, se_W1, se_b1, se_W2, se_b2, xs);
        else
            feat_kernel<0><<<CH / 2, 256, 0, stream>>>(
                item_id + off, likes + off, views + off,
                seq + (size_t)off * HIST_L, item_emb, cate_emb, mm,
                ln_g, ln_b, se_W1, se_b1, se_W2, se_b2, xs);

        // xw GEMM + fused pair epilogue: writes P directly.
        dim3 gxw(CH * 4 / 128, 1);
        gemm_bt<2, 3, 0><<<gxw, 256, 0, stream>>>(
            xs, nullptr, bWt, P, CH * 4, 128, 128, nullptr, nullptr);

        // h1 = relu(BN1([xs|P] @ W1t^T)): K = 1920 (r19 kernel)
        dim3 g1(CH / 256, 4);
        gemm_mlp1<<<g1, 256, 147456, stream>>>(
            xs, P, W1t, h1, CH, 512, 1920, S1, T1);

        // h2 = relu(BN2(h1 @ W2)): K = 512  (h2 overwrites P - dead)
        dim3 g2(CH / 128, 2);
        gemm_bt<0, 1, 0><<<g2, 256, 0, stream>>>(
            h1, nullptr, W2t, h2, CH, 256, 512, S2, T2);

        head_kernel<<<CH / 4, 256, 0, stream>>>(h2, W3, b3, (float*)d_out + off);
    }
}